// Round 6
// baseline (1221.083 us; speedup 1.0000x reference)
//
#include <hip/hip_runtime.h>

#define HD 64
#define SLOPE 0.01f
#define BSH 6                    // 64 nodes per bucket
#define BNODES 64
#define CHUNK 8192               // edges per partition block

// ---------------------------------------------------------------------------
// P0: bucket histogram (bucket = dst >> 6). LDS-staged, one global add per
// (block,bucket).
// ---------------------------------------------------------------------------

__global__ __launch_bounds__(256) void hist_kernel(const int* __restrict__ ei,
                                                   int* __restrict__ bsize,
                                                   int E, int nb) {
    __shared__ int h[784];
    const int t = threadIdx.x;
    for (int i = t; i < nb; i += 256) h[i] = 0;
    __syncthreads();
    const int stride = gridDim.x * 256;
    for (int e = blockIdx.x * 256 + t; e < E; e += stride)
        atomicAdd(&h[ei[E + e] >> BSH], 1);
    __syncthreads();
    for (int i = t; i < nb; i += 256) {
        int v = h[i];
        if (v) atomicAdd(&bsize[i], v);
    }
}

// ---------------------------------------------------------------------------
// P1: exclusive scan of bucket sizes (nb <= 1024), one block; writes base and
// initializes the partition cursors.
// ---------------------------------------------------------------------------

__global__ __launch_bounds__(256) void bscan_kernel(const int* __restrict__ bsize,
                                                    int* __restrict__ bbase,
                                                    int* __restrict__ bcur,
                                                    int nb, int E) {
    __shared__ int wsum[4];
    const int t = threadIdx.x, lane = t & 63, wid = t >> 6;
    int v[4];
    int s = 0;
    #pragma unroll
    for (int j = 0; j < 4; ++j) {
        int i = t * 4 + j;
        v[j] = (i < nb) ? bsize[i] : 0;
        s += v[j];
    }
    int x = s;
    #pragma unroll
    for (int d = 1; d < 64; d <<= 1) { int y = __shfl_up(x, d, 64); if (lane >= d) x += y; }
    if (lane == 63) wsum[wid] = x;
    __syncthreads();
    if (wid == 0 && lane < 4) {
        int ws = wsum[lane], xs = ws;
        #pragma unroll
        for (int d = 1; d < 4; d <<= 1) { int y = __shfl_up(xs, d, 64); if (lane >= d) xs += y; }
        wsum[lane] = xs - ws;
    }
    __syncthreads();
    int base = wsum[wid] + (x - s);
    #pragma unroll
    for (int j = 0; j < 4; ++j) {
        int i = t * 4 + j;
        if (i < nb) { bbase[i] = base; bcur[i] = base; }
        base += v[j];
    }
    if (t == 0) bbase[nb] = E;
}

// ---------------------------------------------------------------------------
// P2: partition edges into bucket-contiguous ebuf. Payload packs src and the
// 6 low dst bits into one int (src < 2^16). Per-chunk LDS ranking gives each
// (block,bucket) one contiguous run -> ~1.5x write amplification instead of
// fill_kernel's 16x.
// ---------------------------------------------------------------------------

__global__ __launch_bounds__(256) void part_kernel(const int* __restrict__ ei,
                                                   int* __restrict__ bcur,
                                                   int* __restrict__ ebuf,
                                                   int E, int nb) {
    __shared__ int pk_s[CHUNK];
    __shared__ int mt_s[CHUNK];
    __shared__ int hist[784];
    __shared__ int sbase[784];
    const int t = threadIdx.x;
    const int c0 = blockIdx.x * CHUNK;
    const int cnt = min(CHUNK, E - c0);
    for (int i = t; i < nb; i += 256) hist[i] = 0;
    __syncthreads();
    for (int i = t; i < cnt; i += 256) {
        int src = ei[c0 + i];
        int dst = ei[E + c0 + i];
        int b = dst >> BSH;
        pk_s[i] = (src << BSH) | (dst & (BNODES - 1));
        int r = atomicAdd(&hist[b], 1);
        mt_s[i] = (b << 13) | r;           // rank < CHUNK = 2^13
    }
    __syncthreads();
    for (int b = t; b < nb; b += 256) {
        int h = hist[b];
        if (h) sbase[b] = atomicAdd(&bcur[b], h);
    }
    __syncthreads();
    for (int i = t; i < cnt; i += 256) {
        int m = mt_s[i];
        int b = m >> 13;
        ebuf[sbase[b] + (m & (CHUNK - 1))] = pk_s[i];
    }
}

// ---------------------------------------------------------------------------
// Aggregation: one block per 64-node bucket. LDS f32 accumulator (stride 68
// -> ~2 addrs/bank on the scatter atomics = free). Wave lane layout:
// s = edge slot (0..3), c4 = float4 chunk (0..15). Packed edge words loaded
// coalesced 64-wide, distributed by __shfl executed by ALL lanes (R3 lesson).
// Degree counted in the same pass -> no count/scan/invdeg infrastructure.
// ---------------------------------------------------------------------------

__global__ __launch_bounds__(512) void agg_kernel(const float* __restrict__ h_in,
                                                  float* __restrict__ mean_out,
                                                  const int* __restrict__ bbase,
                                                  const int* __restrict__ ebuf,
                                                  int n) {
    __shared__ float accum[BNODES * 68];
    __shared__ float cnts[BNODES];
    const int t = threadIdx.x;
    const int lane = t & 63;
    const int w = t >> 6;                  // wave 0..7
    const int s = lane >> 4;
    const int c4 = lane & 15;
    const float4* __restrict__ h4 = (const float4*)h_in;

    for (int i = t; i < BNODES * 68; i += 512) accum[i] = 0.f;
    if (t < BNODES) cnts[t] = 0.f;
    __syncthreads();

    const int b = blockIdx.x;
    const int ebeg = bbase[b];
    const int eend = bbase[b + 1];

    for (int k = ebeg + w * 64; k < eend; k += 512) {
        const int m = min(64, eend - k);
        int pk = (lane < m) ? ebuf[k + lane] : 0;
        const int full = m >> 2;
        #pragma unroll 4
        for (int q = 0; q < full; ++q) {
            int p = __shfl(pk, 4 * q + s, 64);     // all lanes execute
            int src = p >> BSH;
            int d = p & (BNODES - 1);
            float4 v = h4[(size_t)src * 16 + c4];
            float* ap = accum + d * 68 + c4 * 4;
            atomicAdd(ap + 0, v.x);
            atomicAdd(ap + 1, v.y);
            atomicAdd(ap + 2, v.z);
            atomicAdd(ap + 3, v.w);
            if (c4 == 0) atomicAdd(&cnts[d], 1.0f);
        }
        const int rem = m & 3;
        int pr = __shfl(pk, (4 * full + s) & 63, 64);  // outside the branch
        if (s < rem) {
            int src = pr >> BSH;
            int d = pr & (BNODES - 1);
            float4 v = h4[(size_t)src * 16 + c4];
            float* ap = accum + d * 68 + c4 * 4;
            atomicAdd(ap + 0, v.x);
            atomicAdd(ap + 1, v.y);
            atomicAdd(ap + 2, v.z);
            atomicAdd(ap + 3, v.w);
            if (c4 == 0) atomicAdd(&cnts[d], 1.0f);
        }
    }
    __syncthreads();

    // writeout: 8 threads per row, 2 float4 each
    const int r = t >> 3;
    const int q = t & 7;
    const int node = b * BNODES + r;
    if (node < n) {
        float c = cnts[r];
        float invd = 1.0f / ((c > 1.f) ? c : 1.f);
        float4* m4 = (float4*)mean_out;
        #pragma unroll
        for (int j = 0; j < 2; ++j) {
            int ch4 = q * 2 + j;
            float4 vv = *(const float4*)(accum + r * 68 + ch4 * 4);
            float4 o = {vv.x * invd, vv.y * invd, vv.z * invd, vv.w * invd};
            m4[(size_t)node * 16 + ch4] = o;
        }
    }
}

// ---------------------------------------------------------------------------
// Dense: out = leaky(mean @ Wl + bl + self @ Wr), 64x64 tile per block,
// 4x4 register blocking per thread — constant-indexed frags, no spill.
// ---------------------------------------------------------------------------

#define FMA4(acc, am, b0, b1, b2, b3)                                  \
    acc.x += am.x * b0.x + am.y * b1.x + am.z * b2.x + am.w * b3.x;    \
    acc.y += am.x * b0.y + am.y * b1.y + am.z * b2.y + am.w * b3.y;    \
    acc.z += am.x * b0.z + am.y * b1.z + am.z * b2.z + am.w * b3.z;    \
    acc.w += am.x * b0.w + am.y * b1.w + am.z * b2.w + am.w * b3.w;

#define GEMM_BODY(EXTRA_SHARED)                                             \
    __shared__ float sA[64 * 68];                                           \
    __shared__ float sS[64 * 68];                                           \
    __shared__ float sWl[64 * 64];                                          \
    __shared__ float sWr[64 * 64];                                          \
    EXTRA_SHARED                                                            \
    const int t = threadIdx.x;                                              \
    const int r0 = t & 15;                                                  \
    const int j0 = (t >> 4) * 4;                                            \
    const int base = blockIdx.x * 64;                                       \
    const int rows = min(64, n - base);                                     \
    const float4* __restrict__ m4 = (const float4*)mean;                    \
    const float4* __restrict__ h4 = (const float4*)h_in;                    \
    _Pragma("unroll")                                                       \
    for (int idx = 0; idx < 4; ++idx) {                                     \
        int i = t + idx * 256;                                              \
        ((float4*)sWl)[i] = ((const float4*)Wl)[i];                         \
        ((float4*)sWr)[i] = ((const float4*)Wr)[i];                         \
    }                                                                       \
    _Pragma("unroll")                                                       \
    for (int idx = 0; idx < 4; ++idx) {                                     \
        int i = t + idx * 256;                                              \
        int r = i >> 4, c4 = i & 15;                                        \
        float4 va = {0.f, 0.f, 0.f, 0.f}, vs = {0.f, 0.f, 0.f, 0.f};        \
        if (r < rows) {                                                     \
            va = m4[(size_t)(base + r) * 16 + c4];                          \
            vs = h4[(size_t)(base + r) * 16 + c4];                          \
        }                                                                   \
        *(float4*)(sA + r * 68 + 4 * c4) = va;                              \
        *(float4*)(sS + r * 68 + 4 * c4) = vs;                              \
    }                                                                       \
    __syncthreads();                                                        \
    const float4 bias = *(const float4*)(bl + j0);                          \
    float4 acc0 = bias, acc1 = bias, acc2 = bias, acc3 = bias;              \
    _Pragma("unroll 2")                                                     \
    for (int k4 = 0; k4 < 16; ++k4) {                                       \
        float4 b0 = *(const float4*)(sWl + (4 * k4 + 0) * 64 + j0);         \
        float4 b1 = *(const float4*)(sWl + (4 * k4 + 1) * 64 + j0);         \
        float4 b2 = *(const float4*)(sWl + (4 * k4 + 2) * 64 + j0);         \
        float4 b3 = *(const float4*)(sWl + (4 * k4 + 3) * 64 + j0);         \
        float4 a0 = *(const float4*)(sA + (r0 +  0) * 68 + 4 * k4);         \
        float4 a1 = *(const float4*)(sA + (r0 + 16) * 68 + 4 * k4);         \
        float4 a2 = *(const float4*)(sA + (r0 + 32) * 68 + 4 * k4);         \
        float4 a3 = *(const float4*)(sA + (r0 + 48) * 68 + 4 * k4);         \
        FMA4(acc0, a0, b0, b1, b2, b3)                                      \
        FMA4(acc1, a1, b0, b1, b2, b3)                                      \
        FMA4(acc2, a2, b0, b1, b2, b3)                                      \
        FMA4(acc3, a3, b0, b1, b2, b3)                                      \
        b0 = *(const float4*)(sWr + (4 * k4 + 0) * 64 + j0);                \
        b1 = *(const float4*)(sWr + (4 * k4 + 1) * 64 + j0);                \
        b2 = *(const float4*)(sWr + (4 * k4 + 2) * 64 + j0);                \
        b3 = *(const float4*)(sWr + (4 * k4 + 3) * 64 + j0);                \
        a0 = *(const float4*)(sS + (r0 +  0) * 68 + 4 * k4);                \
        a1 = *(const float4*)(sS + (r0 + 16) * 68 + 4 * k4);                \
        a2 = *(const float4*)(sS + (r0 + 32) * 68 + 4 * k4);                \
        a3 = *(const float4*)(sS + (r0 + 48) * 68 + 4 * k4);                \
        FMA4(acc0, a0, b0, b1, b2, b3)                                      \
        FMA4(acc1, a1, b0, b1, b2, b3)                                      \
        FMA4(acc2, a2, b0, b1, b2, b3)                                      \
        FMA4(acc3, a3, b0, b1, b2, b3)                                      \
    }                                                                       \
    acc0.x = (acc0.x > 0.f) ? acc0.x : SLOPE * acc0.x;                      \
    acc0.y = (acc0.y > 0.f) ? acc0.y : SLOPE * acc0.y;                      \
    acc0.z = (acc0.z > 0.f) ? acc0.z : SLOPE * acc0.z;                      \
    acc0.w = (acc0.w > 0.f) ? acc0.w : SLOPE * acc0.w;                      \
    acc1.x = (acc1.x > 0.f) ? acc1.x : SLOPE * acc1.x;                      \
    acc1.y = (acc1.y > 0.f) ? acc1.y : SLOPE * acc1.y;                      \
    acc1.z = (acc1.z > 0.f) ? acc1.z : SLOPE * acc1.z;                      \
    acc1.w = (acc1.w > 0.f) ? acc1.w : SLOPE * acc1.w;                      \
    acc2.x = (acc2.x > 0.f) ? acc2.x : SLOPE * acc2.x;                      \
    acc2.y = (acc2.y > 0.f) ? acc2.y : SLOPE * acc2.y;                      \
    acc2.z = (acc2.z > 0.f) ? acc2.z : SLOPE * acc2.z;                      \
    acc2.w = (acc2.w > 0.f) ? acc2.w : SLOPE * acc2.w;                      \
    acc3.x = (acc3.x > 0.f) ? acc3.x : SLOPE * acc3.x;                      \
    acc3.y = (acc3.y > 0.f) ? acc3.y : SLOPE * acc3.y;                      \
    acc3.z = (acc3.z > 0.f) ? acc3.z : SLOPE * acc3.z;                      \
    acc3.w = (acc3.w > 0.f) ? acc3.w : SLOPE * acc3.w;

__global__ __launch_bounds__(256, 2) void sage_gemm(
    const float* __restrict__ mean, const float* __restrict__ h_in,
    float* __restrict__ h_out,
    const float* __restrict__ Wl, const float* __restrict__ bl,
    const float* __restrict__ Wr, int n) {
    GEMM_BODY()
    #define STORE_ROW(S, ACC)                                               \
        { int r = r0 + 16 * S;                                              \
          if (r < rows)                                                     \
              *(float4*)(h_out + (size_t)(base + r) * HD + j0) = ACC; }
    STORE_ROW(0, acc0)
    STORE_ROW(1, acc1)
    STORE_ROW(2, acc2)
    STORE_ROW(3, acc3)
    #undef STORE_ROW
}

// Layer-3 variant: h3 never hits memory — dot with Wout, cross-wave LDS
// reduction, write out[node] directly.
__global__ __launch_bounds__(256, 2) void sage_gemm_out(
    const float* __restrict__ mean, const float* __restrict__ h_in,
    const float* __restrict__ Wl, const float* __restrict__ bl,
    const float* __restrict__ Wr,
    const float* __restrict__ Wout, const float* __restrict__ bout,
    float* __restrict__ out, int n) {
    GEMM_BODY(__shared__ float s_part[16][64];)
    const float4 w4 = *(const float4*)(Wout + j0);
    const int jg = t >> 4;
    s_part[jg][r0 +  0] = acc0.x * w4.x + acc0.y * w4.y + acc0.z * w4.z + acc0.w * w4.w;
    s_part[jg][r0 + 16] = acc1.x * w4.x + acc1.y * w4.y + acc1.z * w4.z + acc1.w * w4.w;
    s_part[jg][r0 + 32] = acc2.x * w4.x + acc2.y * w4.y + acc2.z * w4.z + acc2.w * w4.w;
    s_part[jg][r0 + 48] = acc3.x * w4.x + acc3.y * w4.y + acc3.z * w4.z + acc3.w * w4.w;
    __syncthreads();
    if (t < 64) {
        float sum = 0.f;
        #pragma unroll
        for (int g = 0; g < 16; ++g) sum += s_part[g][t];
        if (t < rows) out[base + t] = sum + bout[0];
    }
}

// ---------------------------------------------------------------------------

extern "C" void kernel_launch(void* const* d_in, const int* in_sizes, int n_in,
                              void* d_out, int out_size, void* d_ws, size_t ws_size,
                              hipStream_t stream) {
    const float* x   = (const float*)d_in[0];
    const int* ei    = (const int*)d_in[1];
    const float* Wl1 = (const float*)d_in[2];
    const float* bl1 = (const float*)d_in[3];
    const float* Wr1 = (const float*)d_in[4];
    const float* Wl2 = (const float*)d_in[5];
    const float* bl2 = (const float*)d_in[6];
    const float* Wr2 = (const float*)d_in[7];
    const float* Wl3 = (const float*)d_in[8];
    const float* bl3 = (const float*)d_in[9];
    const float* Wr3 = (const float*)d_in[10];
    const float* Wout = (const float*)d_in[11];
    const float* bout = (const float*)d_in[12];
    float* out = (float*)d_out;

    const int N = in_sizes[0] / HD;       // 50000
    const int E = in_sizes[1] / 2;        // 800000
    const int NB = (N + BNODES - 1) >> BSH;   // 782 buckets

    // Workspace layout — float4-accessed buffers first (16B alignment).
    float* hMean = (float*)d_ws;                    // [N*64]
    float* hA    = hMean + (size_t)N * HD;          // [N*64]
    float* hB    = hA + (size_t)N * HD;             // [N*64]
    int* ebuf    = (int*)(hB + (size_t)N * HD);     // [E] packed (src<<6|dstLow)
    int* bsize   = ebuf + E;                        // [784]
    int* bbase   = bsize + 784;                     // [784]
    int* bcur    = bbase + 784;                     // [784]

    hipMemsetAsync(bsize, 0, 784 * sizeof(int), stream);

    hist_kernel<<<128, 256, 0, stream>>>(ei, bsize, E, NB);
    bscan_kernel<<<1, 256, 0, stream>>>(bsize, bbase, bcur, NB, E);
    part_kernel<<<(E + CHUNK - 1) / CHUNK, 256, 0, stream>>>(ei, bcur, ebuf, E, NB);

    const int ggrid = (N + 63) / 64;      // 782 tiles

    agg_kernel<<<NB, 512, 0, stream>>>(x, hMean, bbase, ebuf, N);
    sage_gemm<<<ggrid, 256, 0, stream>>>(hMean, x, hA, Wl1, bl1, Wr1, N);

    agg_kernel<<<NB, 512, 0, stream>>>(hA, hMean, bbase, ebuf, N);
    sage_gemm<<<ggrid, 256, 0, stream>>>(hMean, hA, hB, Wl2, bl2, Wr2, N);

    agg_kernel<<<NB, 512, 0, stream>>>(hB, hMean, bbase, ebuf, N);
    sage_gemm_out<<<ggrid, 256, 0, stream>>>(hMean, hB, Wl3, bl3, Wr3, Wout, bout, out, N);
}

// Round 7
// 337.232 us; speedup vs baseline: 3.6209x; 3.6209x over previous
//
#include <hip/hip_runtime.h>

#define HD 64
#define SLOPE 0.01f

// ---------------------------------------------------------------------------
// CSR build: count -> 3-phase scan -> fill.  (R5-proven, untouched.)
// ---------------------------------------------------------------------------

__global__ __launch_bounds__(256) void count_kernel(const int* __restrict__ ei,
                                                    int* __restrict__ deg, int E) {
    int e = blockIdx.x * blockDim.x + threadIdx.x;
    if (e < E) atomicAdd(&deg[ei[E + e]], 1);   // row 1 = dst
}

__global__ __launch_bounds__(256) void scan_p1(const int* __restrict__ deg,
                                               int* __restrict__ rowptr,
                                               float* __restrict__ invdeg,
                                               int* __restrict__ bsum, int n) {
    __shared__ int wsum[4];
    const int t = threadIdx.x, lane = t & 63, wid = t >> 6;
    const int i = blockIdx.x * 256 + t;
    int v = (i < n) ? deg[i] : 0;
    int x = v;
    #pragma unroll
    for (int d = 1; d < 64; d <<= 1) { int y = __shfl_up(x, d, 64); if (lane >= d) x += y; }
    if (lane == 63) wsum[wid] = x;
    __syncthreads();
    if (wid == 0 && lane < 4) {
        int ws = wsum[lane], xs = ws;
        #pragma unroll
        for (int d = 1; d < 4; d <<= 1) { int y = __shfl_up(xs, d, 64); if (lane >= d) xs += y; }
        wsum[lane] = xs - ws;
    }
    __syncthreads();
    int excl = wsum[wid] + (x - v);
    if (i < n) {
        rowptr[i] = excl;
        invdeg[i] = 1.0f / (float)((v > 1) ? v : 1);
    }
    if (t == 255) bsum[blockIdx.x] = excl + v;
}

__global__ __launch_bounds__(256) void scan_p2(int* __restrict__ bsum, int nb) {
    __shared__ int wsum[4];
    const int t = threadIdx.x, lane = t & 63, wid = t >> 6;
    int v = (t < nb) ? bsum[t] : 0;
    int x = v;
    #pragma unroll
    for (int d = 1; d < 64; d <<= 1) { int y = __shfl_up(x, d, 64); if (lane >= d) x += y; }
    if (lane == 63) wsum[wid] = x;
    __syncthreads();
    if (wid == 0 && lane < 4) {
        int ws = wsum[lane], xs = ws;
        #pragma unroll
        for (int d = 1; d < 4; d <<= 1) { int y = __shfl_up(xs, d, 64); if (lane >= d) xs += y; }
        wsum[lane] = xs - ws;
    }
    __syncthreads();
    if (t < nb) bsum[t] = wsum[wid] + (x - v);
}

__global__ __launch_bounds__(256) void scan_p3(int* __restrict__ rowptr,
                                               int* __restrict__ cursor,
                                               const int* __restrict__ bsum,
                                               int n, int E) {
    int i = blockIdx.x * 256 + threadIdx.x;
    if (i < n) {
        int v = rowptr[i] + bsum[blockIdx.x];
        rowptr[i] = v;
        cursor[i] = v;
    }
    if (i == 0) rowptr[n] = E;
}

__global__ __launch_bounds__(256) void fill_kernel(const int* __restrict__ ei,
                                                   int* __restrict__ cursor,
                                                   int* __restrict__ colidx, int E) {
    int e = blockIdx.x * blockDim.x + threadIdx.x;
    if (e < E) {
        int src = ei[e];
        int dst = ei[E + e];
        int pos = atomicAdd(&cursor[dst], 1);   // absolute slot (cursor=rowptr)
        colidx[pos] = src;
    }
}

// ---------------------------------------------------------------------------
// Aggregation v3: 4 nodes per wave, one 16-lane group per node. Each group's
// 16 lanes hold the node's f4-chunked running sum directly -> no butterfly
// reduction. Per j-iteration one load instruction gathers 4 independent rows
// (one per group); unroll 4 -> 16 rows in flight per wave (R5 had 4 -> this
// attacks the latency-bound regime the counters showed).
// All __shfl executed by ALL lanes (R3 lesson); the use-predicate t0+j<deg
// is exactly the condition for the sourced lane's ci to be valid.
// ---------------------------------------------------------------------------

__global__ __launch_bounds__(256) void aggregate_kernel(
    const float* __restrict__ h_in, float* __restrict__ mean_out,
    const int* __restrict__ rowptr, const int* __restrict__ colidx,
    const float* __restrict__ inv_deg, int n) {
    const int lane = threadIdx.x & 63;
    const int wslot = threadIdx.x >> 6;
    const int g = lane >> 4;     // node slot within tile (0..3)
    const int c4 = lane & 15;    // float4 chunk of the 64-ch row
    const float4* __restrict__ h4 = (const float4*)h_in;
    float4* __restrict__ m4 = (float4*)mean_out;

    const int ntiles = gridDim.x * 4;
    const int ntile_tot = (n + 3) >> 2;

    for (int tile = blockIdx.x * 4 + wslot; tile < ntile_tot; tile += ntiles) {
        const int node = tile * 4 + g;
        const bool valid = node < n;
        int beg = 0, end = 0; float idg = 0.f;
        if (valid) {
            beg = rowptr[node];
            end = rowptr[node + 1];
            idg = inv_deg[node];
        }
        const int deg = end - beg;

        // wave-uniform max degree over the 4 groups (xor over lane bits 4,5)
        int md = deg;
        md = max(md, __shfl_xor(md, 16, 64));
        md = max(md, __shfl_xor(md, 32, 64));

        float4 acc = {0.f, 0.f, 0.f, 0.f};
        for (int t0 = 0; t0 < md; t0 += 16) {
            int ci = 0;
            const int off = beg + t0 + c4;
            if (off < end) ci = colidx[off];    // 4 coalesced 64B segments
            const int jmax = (md - t0 < 16) ? (md - t0) : 16;
            #pragma unroll 4
            for (int j = 0; j < 16; ++j) {
                if (j >= jmax) break;                    // wave-uniform
                int idx = __shfl(ci, g * 16 + j, 64);    // all lanes execute
                if (t0 + j < deg) {                      // group-uniform
                    float4 v = h4[(size_t)idx * 16 + c4];
                    acc.x += v.x; acc.y += v.y; acc.z += v.z; acc.w += v.w;
                }
            }
        }
        if (valid) {
            float4 o = {acc.x * idg, acc.y * idg, acc.z * idg, acc.w * idg};
            m4[(size_t)node * 16 + c4] = o;    // wave stores 4 rows = 1KB
        }
    }
}

// ---------------------------------------------------------------------------
// Dense: out = leaky(mean @ Wl + bl + self @ Wr), 64x64 tile per block,
// 4x4 register blocking per thread — constant-indexed frags, no spill.
// ---------------------------------------------------------------------------

#define FMA4(acc, am, b0, b1, b2, b3)                                  \
    acc.x += am.x * b0.x + am.y * b1.x + am.z * b2.x + am.w * b3.x;    \
    acc.y += am.x * b0.y + am.y * b1.y + am.z * b2.y + am.w * b3.y;    \
    acc.z += am.x * b0.z + am.y * b1.z + am.z * b2.z + am.w * b3.z;    \
    acc.w += am.x * b0.w + am.y * b1.w + am.z * b2.w + am.w * b3.w;

#define GEMM_BODY(EXTRA_SHARED)                                             \
    __shared__ float sA[64 * 68];                                           \
    __shared__ float sS[64 * 68];                                           \
    __shared__ float sWl[64 * 64];                                          \
    __shared__ float sWr[64 * 64];                                          \
    EXTRA_SHARED                                                            \
    const int t = threadIdx.x;                                              \
    const int r0 = t & 15;                                                  \
    const int j0 = (t >> 4) * 4;                                            \
    const int base = blockIdx.x * 64;                                       \
    const int rows = min(64, n - base);                                     \
    const float4* __restrict__ m4 = (const float4*)mean;                    \
    const float4* __restrict__ h4 = (const float4*)h_in;                    \
    _Pragma("unroll")                                                       \
    for (int idx = 0; idx < 4; ++idx) {                                     \
        int i = t + idx * 256;                                              \
        ((float4*)sWl)[i] = ((const float4*)Wl)[i];                         \
        ((float4*)sWr)[i] = ((const float4*)Wr)[i];                         \
    }                                                                       \
    _Pragma("unroll")                                                       \
    for (int idx = 0; idx < 4; ++idx) {                                     \
        int i = t + idx * 256;                                              \
        int r = i >> 4, c4 = i & 15;                                        \
        float4 va = {0.f, 0.f, 0.f, 0.f}, vs = {0.f, 0.f, 0.f, 0.f};        \
        if (r < rows) {                                                     \
            va = m4[(size_t)(base + r) * 16 + c4];                          \
            vs = h4[(size_t)(base + r) * 16 + c4];                          \
        }                                                                   \
        *(float4*)(sA + r * 68 + 4 * c4) = va;                              \
        *(float4*)(sS + r * 68 + 4 * c4) = vs;                              \
    }                                                                       \
    __syncthreads();                                                        \
    const float4 bias = *(const float4*)(bl + j0);                          \
    float4 acc0 = bias, acc1 = bias, acc2 = bias, acc3 = bias;              \
    _Pragma("unroll 2")                                                     \
    for (int k4 = 0; k4 < 16; ++k4) {                                       \
        float4 b0 = *(const float4*)(sWl + (4 * k4 + 0) * 64 + j0);         \
        float4 b1 = *(const float4*)(sWl + (4 * k4 + 1) * 64 + j0);         \
        float4 b2 = *(const float4*)(sWl + (4 * k4 + 2) * 64 + j0);         \
        float4 b3 = *(const float4*)(sWl + (4 * k4 + 3) * 64 + j0);         \
        float4 a0 = *(const float4*)(sA + (r0 +  0) * 68 + 4 * k4);         \
        float4 a1 = *(const float4*)(sA + (r0 + 16) * 68 + 4 * k4);         \
        float4 a2 = *(const float4*)(sA + (r0 + 32) * 68 + 4 * k4);         \
        float4 a3 = *(const float4*)(sA + (r0 + 48) * 68 + 4 * k4);         \
        FMA4(acc0, a0, b0, b1, b2, b3)                                      \
        FMA4(acc1, a1, b0, b1, b2, b3)                                      \
        FMA4(acc2, a2, b0, b1, b2, b3)                                      \
        FMA4(acc3, a3, b0, b1, b2, b3)                                      \
        b0 = *(const float4*)(sWr + (4 * k4 + 0) * 64 + j0);                \
        b1 = *(const float4*)(sWr + (4 * k4 + 1) * 64 + j0);                \
        b2 = *(const float4*)(sWr + (4 * k4 + 2) * 64 + j0);                \
        b3 = *(const float4*)(sWr + (4 * k4 + 3) * 64 + j0);                \
        a0 = *(const float4*)(sS + (r0 +  0) * 68 + 4 * k4);                \
        a1 = *(const float4*)(sS + (r0 + 16) * 68 + 4 * k4);                \
        a2 = *(const float4*)(sS + (r0 + 32) * 68 + 4 * k4);                \
        a3 = *(const float4*)(sS + (r0 + 48) * 68 + 4 * k4);                \
        FMA4(acc0, a0, b0, b1, b2, b3)                                      \
        FMA4(acc1, a1, b0, b1, b2, b3)                                      \
        FMA4(acc2, a2, b0, b1, b2, b3)                                      \
        FMA4(acc3, a3, b0, b1, b2, b3)                                      \
    }                                                                       \
    acc0.x = (acc0.x > 0.f) ? acc0.x : SLOPE * acc0.x;                      \
    acc0.y = (acc0.y > 0.f) ? acc0.y : SLOPE * acc0.y;                      \
    acc0.z = (acc0.z > 0.f) ? acc0.z : SLOPE * acc0.z;                      \
    acc0.w = (acc0.w > 0.f) ? acc0.w : SLOPE * acc0.w;                      \
    acc1.x = (acc1.x > 0.f) ? acc1.x : SLOPE * acc1.x;                      \
    acc1.y = (acc1.y > 0.f) ? acc1.y : SLOPE * acc1.y;                      \
    acc1.z = (acc1.z > 0.f) ? acc1.z : SLOPE * acc1.z;                      \
    acc1.w = (acc1.w > 0.f) ? acc1.w : SLOPE * acc1.w;                      \
    acc2.x = (acc2.x > 0.f) ? acc2.x : SLOPE * acc2.x;                      \
    acc2.y = (acc2.y > 0.f) ? acc2.y : SLOPE * acc2.y;                      \
    acc2.z = (acc2.z > 0.f) ? acc2.z : SLOPE * acc2.z;                      \
    acc2.w = (acc2.w > 0.f) ? acc2.w : SLOPE * acc2.w;                      \
    acc3.x = (acc3.x > 0.f) ? acc3.x : SLOPE * acc3.x;                      \
    acc3.y = (acc3.y > 0.f) ? acc3.y : SLOPE * acc3.y;                      \
    acc3.z = (acc3.z > 0.f) ? acc3.z : SLOPE * acc3.z;                      \
    acc3.w = (acc3.w > 0.f) ? acc3.w : SLOPE * acc3.w;

__global__ __launch_bounds__(256, 2) void sage_gemm(
    const float* __restrict__ mean, const float* __restrict__ h_in,
    float* __restrict__ h_out,
    const float* __restrict__ Wl, const float* __restrict__ bl,
    const float* __restrict__ Wr, int n) {
    GEMM_BODY()
    #define STORE_ROW(S, ACC)                                               \
        { int r = r0 + 16 * S;                                              \
          if (r < rows)                                                     \
              *(float4*)(h_out + (size_t)(base + r) * HD + j0) = ACC; }
    STORE_ROW(0, acc0)
    STORE_ROW(1, acc1)
    STORE_ROW(2, acc2)
    STORE_ROW(3, acc3)
    #undef STORE_ROW
}

// Layer-3 variant: h3 never hits memory — dot with Wout, cross-wave LDS
// reduction, write out[node] directly.
__global__ __launch_bounds__(256, 2) void sage_gemm_out(
    const float* __restrict__ mean, const float* __restrict__ h_in,
    const float* __restrict__ Wl, const float* __restrict__ bl,
    const float* __restrict__ Wr,
    const float* __restrict__ Wout, const float* __restrict__ bout,
    float* __restrict__ out, int n) {
    GEMM_BODY(__shared__ float s_part[16][64];)
    const float4 w4 = *(const float4*)(Wout + j0);
    const int jg = t >> 4;
    s_part[jg][r0 +  0] = acc0.x * w4.x + acc0.y * w4.y + acc0.z * w4.z + acc0.w * w4.w;
    s_part[jg][r0 + 16] = acc1.x * w4.x + acc1.y * w4.y + acc1.z * w4.z + acc1.w * w4.w;
    s_part[jg][r0 + 32] = acc2.x * w4.x + acc2.y * w4.y + acc2.z * w4.z + acc2.w * w4.w;
    s_part[jg][r0 + 48] = acc3.x * w4.x + acc3.y * w4.y + acc3.z * w4.z + acc3.w * w4.w;
    __syncthreads();
    if (t < 64) {
        float sum = 0.f;
        #pragma unroll
        for (int g = 0; g < 16; ++g) sum += s_part[g][t];
        if (t < rows) out[base + t] = sum + bout[0];
    }
}

// ---------------------------------------------------------------------------

extern "C" void kernel_launch(void* const* d_in, const int* in_sizes, int n_in,
                              void* d_out, int out_size, void* d_ws, size_t ws_size,
                              hipStream_t stream) {
    const float* x   = (const float*)d_in[0];
    const int* ei    = (const int*)d_in[1];
    const float* Wl1 = (const float*)d_in[2];
    const float* bl1 = (const float*)d_in[3];
    const float* Wr1 = (const float*)d_in[4];
    const float* Wl2 = (const float*)d_in[5];
    const float* bl2 = (const float*)d_in[6];
    const float* Wr2 = (const float*)d_in[7];
    const float* Wl3 = (const float*)d_in[8];
    const float* bl3 = (const float*)d_in[9];
    const float* Wr3 = (const float*)d_in[10];
    const float* Wout = (const float*)d_in[11];
    const float* bout = (const float*)d_in[12];
    float* out = (float*)d_out;

    const int N = in_sizes[0] / HD;       // 50000
    const int E = in_sizes[1] / 2;        // 800000

    // Workspace layout — float4-accessed buffers first (16B alignment).
    float* hMean  = (float*)d_ws;                   // [N*64]
    float* hA     = hMean + (size_t)N * HD;         // [N*64]
    float* hB     = hA + (size_t)N * HD;            // [N*64]
    int* deg      = (int*)(hB + (size_t)N * HD);    // [N]
    int* cursor   = deg + N;                        // [N]
    int* rowptr   = cursor + N;                     // [N+1]
    float* invdeg = (float*)(rowptr + N + 1);       // [N]
    int* colidx   = (int*)(invdeg + N);             // [E]
    int* bsum     = colidx + E;                     // [<=256]

    hipMemsetAsync(deg, 0, (size_t)N * sizeof(int), stream);

    const int eb = (E + 255) / 256;
    const int nb = (N + 255) / 256;       // 196 <= 256
    count_kernel<<<eb, 256, 0, stream>>>(ei, deg, E);
    scan_p1<<<nb, 256, 0, stream>>>(deg, rowptr, invdeg, bsum, N);
    scan_p2<<<1, 256, 0, stream>>>(bsum, nb);
    scan_p3<<<nb, 256, 0, stream>>>(rowptr, cursor, bsum, N, E);
    fill_kernel<<<eb, 256, 0, stream>>>(ei, cursor, colidx, E);

    const int agrid = 2048;               // 8192 waves, grid-stride over tiles
    const int ggrid = (N + 63) / 64;      // 782 tiles

    aggregate_kernel<<<agrid, 256, 0, stream>>>(x, hMean, rowptr, colidx, invdeg, N);
    sage_gemm<<<ggrid, 256, 0, stream>>>(hMean, x, hA, Wl1, bl1, Wr1, N);

    aggregate_kernel<<<agrid, 256, 0, stream>>>(hA, hMean, rowptr, colidx, invdeg, N);
    sage_gemm<<<ggrid, 256, 0, stream>>>(hMean, hA, hB, Wl2, bl2, Wr2, N);

    aggregate_kernel<<<agrid, 256, 0, stream>>>(hB, hMean, rowptr, colidx, invdeg, N);
    sage_gemm_out<<<ggrid, 256, 0, stream>>>(hMean, hB, Wl3, bl3, Wr3, Wout, bout, out, N);
}

// Round 8
// 282.248 us; speedup vs baseline: 4.3263x; 1.1948x over previous
//
#include <hip/hip_runtime.h>

#define HD 64
#define SLOPE 0.01f
#define BSH 6                    // 64 nodes per bucket
#define BNODES 64
#define CHUNK 8192               // edges per partition block

// ---------------------------------------------------------------------------
// Build v3: bucket histogram -> scan -> localized partition -> per-bucket
// counting sort. Produces standard CSR (colidx/rowptr/invdeg) with ~1.5x
// write amplification instead of fill_kernel's 16x (53 MB -> ~8 MB).
// hist/bscan/part are R6-proven verbatim.
// ---------------------------------------------------------------------------

__global__ __launch_bounds__(256) void hist_kernel(const int* __restrict__ ei,
                                                   int* __restrict__ bsize,
                                                   int E, int nb) {
    __shared__ int h[784];
    const int t = threadIdx.x;
    for (int i = t; i < nb; i += 256) h[i] = 0;
    __syncthreads();
    const int stride = gridDim.x * 256;
    for (int e = blockIdx.x * 256 + t; e < E; e += stride)
        atomicAdd(&h[ei[E + e] >> BSH], 1);
    __syncthreads();
    for (int i = t; i < nb; i += 256) {
        int v = h[i];
        if (v) atomicAdd(&bsize[i], v);
    }
}

__global__ __launch_bounds__(256) void bscan_kernel(const int* __restrict__ bsize,
                                                    int* __restrict__ bbase,
                                                    int* __restrict__ bcur,
                                                    int nb, int E) {
    __shared__ int wsum[4];
    const int t = threadIdx.x, lane = t & 63, wid = t >> 6;
    int v[4];
    int s = 0;
    #pragma unroll
    for (int j = 0; j < 4; ++j) {
        int i = t * 4 + j;
        v[j] = (i < nb) ? bsize[i] : 0;
        s += v[j];
    }
    int x = s;
    #pragma unroll
    for (int d = 1; d < 64; d <<= 1) { int y = __shfl_up(x, d, 64); if (lane >= d) x += y; }
    if (lane == 63) wsum[wid] = x;
    __syncthreads();
    if (wid == 0 && lane < 4) {
        int ws = wsum[lane], xs = ws;
        #pragma unroll
        for (int d = 1; d < 4; d <<= 1) { int y = __shfl_up(xs, d, 64); if (lane >= d) xs += y; }
        wsum[lane] = xs - ws;
    }
    __syncthreads();
    int base = wsum[wid] + (x - s);
    #pragma unroll
    for (int j = 0; j < 4; ++j) {
        int i = t * 4 + j;
        if (i < nb) { bbase[i] = base; bcur[i] = base; }
        base += v[j];
    }
    if (t == 0) bbase[nb] = E;
}

__global__ __launch_bounds__(256) void part_kernel(const int* __restrict__ ei,
                                                   int* __restrict__ bcur,
                                                   int* __restrict__ ebuf,
                                                   int E, int nb) {
    __shared__ int pk_s[CHUNK];
    __shared__ int mt_s[CHUNK];
    __shared__ int hist[784];
    __shared__ int sbase[784];
    const int t = threadIdx.x;
    const int c0 = blockIdx.x * CHUNK;
    const int cnt = min(CHUNK, E - c0);
    for (int i = t; i < nb; i += 256) hist[i] = 0;
    __syncthreads();
    for (int i = t; i < cnt; i += 256) {
        int src = ei[c0 + i];
        int dst = ei[E + c0 + i];
        int b = dst >> BSH;
        pk_s[i] = (src << BSH) | (dst & (BNODES - 1));
        int r = atomicAdd(&hist[b], 1);
        mt_s[i] = (b << 13) | r;           // rank < CHUNK = 2^13
    }
    __syncthreads();
    for (int b = t; b < nb; b += 256) {
        int h = hist[b];
        if (h) sbase[b] = atomicAdd(&bcur[b], h);
    }
    __syncthreads();
    for (int i = t; i < cnt; i += 256) {
        int m = mt_s[i];
        int b = m >> 13;
        ebuf[sbase[b] + (m & (CHUNK - 1))] = pk_s[i];
    }
}

// One block per bucket: counting-sort by dst&63 -> CSR colidx (writes land
// inside the bucket's own ~4KB region = coalesced in L2), rowptr, invdeg.
__global__ __launch_bounds__(256) void bsort_kernel(const int* __restrict__ ebuf,
                                                    const int* __restrict__ bbase,
                                                    int* __restrict__ colidx,
                                                    int* __restrict__ rowptr,
                                                    float* __restrict__ invdeg,
                                                    int n, int E) {
    __shared__ int cnt[BNODES];
    const int b = blockIdx.x;
    const int t = threadIdx.x;
    const int ebeg = bbase[b], eend = bbase[b + 1];
    if (t < BNODES) cnt[t] = 0;
    __syncthreads();
    for (int k = ebeg + t; k < eend; k += 256)
        atomicAdd(&cnt[ebuf[k] & (BNODES - 1)], 1);
    __syncthreads();
    if (t < BNODES) {                      // wave 0: scan the 64 counters
        int v = cnt[t];
        int x = v;
        #pragma unroll
        for (int d = 1; d < 64; d <<= 1) { int y = __shfl_up(x, d, 64); if (t >= d) x += y; }
        int excl = x - v;
        int node = b * BNODES + t;
        if (node < n) {
            rowptr[node] = ebeg + excl;
            invdeg[node] = 1.0f / (float)((v > 1) ? v : 1);
        }
        cnt[t] = excl;                     // becomes the running cursor
    }
    if (b == 0 && t == 0) rowptr[n] = E;
    __syncthreads();
    for (int k = ebeg + t; k < eend; k += 256) {
        int p = ebuf[k];
        int r = atomicAdd(&cnt[p & (BNODES - 1)], 1);
        colidx[ebeg + r] = p >> BSH;
    }
}

// ---------------------------------------------------------------------------
// Aggregation (R7 v3, unchanged): 4 nodes per wave, one 16-lane group per
// node; 16 rows in flight per wave. All __shfl executed by ALL lanes.
// ---------------------------------------------------------------------------

__global__ __launch_bounds__(256) void aggregate_kernel(
    const float* __restrict__ h_in, float* __restrict__ mean_out,
    const int* __restrict__ rowptr, const int* __restrict__ colidx,
    const float* __restrict__ inv_deg, int n) {
    const int lane = threadIdx.x & 63;
    const int wslot = threadIdx.x >> 6;
    const int g = lane >> 4;     // node slot within tile (0..3)
    const int c4 = lane & 15;    // float4 chunk of the 64-ch row
    const float4* __restrict__ h4 = (const float4*)h_in;
    float4* __restrict__ m4 = (float4*)mean_out;

    const int ntiles = gridDim.x * 4;
    const int ntile_tot = (n + 3) >> 2;

    for (int tile = blockIdx.x * 4 + wslot; tile < ntile_tot; tile += ntiles) {
        const int node = tile * 4 + g;
        const bool valid = node < n;
        int beg = 0, end = 0; float idg = 0.f;
        if (valid) {
            beg = rowptr[node];
            end = rowptr[node + 1];
            idg = inv_deg[node];
        }
        const int deg = end - beg;

        int md = deg;
        md = max(md, __shfl_xor(md, 16, 64));
        md = max(md, __shfl_xor(md, 32, 64));

        float4 acc = {0.f, 0.f, 0.f, 0.f};
        for (int t0 = 0; t0 < md; t0 += 16) {
            int ci = 0;
            const int off = beg + t0 + c4;
            if (off < end) ci = colidx[off];    // 4 coalesced 64B segments
            const int jmax = (md - t0 < 16) ? (md - t0) : 16;
            #pragma unroll 4
            for (int j = 0; j < 16; ++j) {
                if (j >= jmax) break;                    // wave-uniform
                int idx = __shfl(ci, g * 16 + j, 64);    // all lanes execute
                if (t0 + j < deg) {                      // group-uniform
                    float4 v = h4[(size_t)idx * 16 + c4];
                    acc.x += v.x; acc.y += v.y; acc.z += v.z; acc.w += v.w;
                }
            }
        }
        if (valid) {
            float4 o = {acc.x * idg, acc.y * idg, acc.z * idg, acc.w * idg};
            m4[(size_t)node * 16 + c4] = o;    // wave stores 4 rows = 1KB
        }
    }
}

// ---------------------------------------------------------------------------
// Dense: out = leaky(mean @ Wl + bl + self @ Wr), 64x64 tile per block,
// 4x4 register blocking per thread — constant-indexed frags, no spill.
// ---------------------------------------------------------------------------

#define FMA4(acc, am, b0, b1, b2, b3)                                  \
    acc.x += am.x * b0.x + am.y * b1.x + am.z * b2.x + am.w * b3.x;    \
    acc.y += am.x * b0.y + am.y * b1.y + am.z * b2.y + am.w * b3.y;    \
    acc.z += am.x * b0.z + am.y * b1.z + am.z * b2.z + am.w * b3.z;    \
    acc.w += am.x * b0.w + am.y * b1.w + am.z * b2.w + am.w * b3.w;

#define GEMM_BODY(EXTRA_SHARED)                                             \
    __shared__ float sA[64 * 68];                                           \
    __shared__ float sS[64 * 68];                                           \
    __shared__ float sWl[64 * 64];                                          \
    __shared__ float sWr[64 * 64];                                          \
    EXTRA_SHARED                                                            \
    const int t = threadIdx.x;                                              \
    const int r0 = t & 15;                                                  \
    const int j0 = (t >> 4) * 4;                                            \
    const int base = blockIdx.x * 64;                                       \
    const int rows = min(64, n - base);                                     \
    const float4* __restrict__ m4 = (const float4*)mean;                    \
    const float4* __restrict__ h4 = (const float4*)h_in;                    \
    _Pragma("unroll")                                                       \
    for (int idx = 0; idx < 4; ++idx) {                                     \
        int i = t + idx * 256;                                              \
        ((float4*)sWl)[i] = ((const float4*)Wl)[i];                         \
        ((float4*)sWr)[i] = ((const float4*)Wr)[i];                         \
    }                                                                       \
    _Pragma("unroll")                                                       \
    for (int idx = 0; idx < 4; ++idx) {                                     \
        int i = t + idx * 256;                                              \
        int r = i >> 4, c4 = i & 15;                                        \
        float4 va = {0.f, 0.f, 0.f, 0.f}, vs = {0.f, 0.f, 0.f, 0.f};        \
        if (r < rows) {                                                     \
            va = m4[(size_t)(base + r) * 16 + c4];                          \
            vs = h4[(size_t)(base + r) * 16 + c4];                          \
        }                                                                   \
        *(float4*)(sA + r * 68 + 4 * c4) = va;                              \
        *(float4*)(sS + r * 68 + 4 * c4) = vs;                              \
    }                                                                       \
    __syncthreads();                                                        \
    const float4 bias = *(const float4*)(bl + j0);                          \
    float4 acc0 = bias, acc1 = bias, acc2 = bias, acc3 = bias;              \
    _Pragma("unroll 2")                                                     \
    for (int k4 = 0; k4 < 16; ++k4) {                                       \
        float4 b0 = *(const float4*)(sWl + (4 * k4 + 0) * 64 + j0);         \
        float4 b1 = *(const float4*)(sWl + (4 * k4 + 1) * 64 + j0);         \
        float4 b2 = *(const float4*)(sWl + (4 * k4 + 2) * 64 + j0);         \
        float4 b3 = *(const float4*)(sWl + (4 * k4 + 3) * 64 + j0);         \
        float4 a0 = *(const float4*)(sA + (r0 +  0) * 68 + 4 * k4);         \
        float4 a1 = *(const float4*)(sA + (r0 + 16) * 68 + 4 * k4);         \
        float4 a2 = *(const float4*)(sA + (r0 + 32) * 68 + 4 * k4);         \
        float4 a3 = *(const float4*)(sA + (r0 + 48) * 68 + 4 * k4);         \
        FMA4(acc0, a0, b0, b1, b2, b3)                                      \
        FMA4(acc1, a1, b0, b1, b2, b3)                                      \
        FMA4(acc2, a2, b0, b1, b2, b3)                                      \
        FMA4(acc3, a3, b0, b1, b2, b3)                                      \
        b0 = *(const float4*)(sWr + (4 * k4 + 0) * 64 + j0);                \
        b1 = *(const float4*)(sWr + (4 * k4 + 1) * 64 + j0);                \
        b2 = *(const float4*)(sWr + (4 * k4 + 2) * 64 + j0);                \
        b3 = *(const float4*)(sWr + (4 * k4 + 3) * 64 + j0);                \
        a0 = *(const float4*)(sS + (r0 +  0) * 68 + 4 * k4);                \
        a1 = *(const float4*)(sS + (r0 + 16) * 68 + 4 * k4);                \
        a2 = *(const float4*)(sS + (r0 + 32) * 68 + 4 * k4);                \
        a3 = *(const float4*)(sS + (r0 + 48) * 68 + 4 * k4);                \
        FMA4(acc0, a0, b0, b1, b2, b3)                                      \
        FMA4(acc1, a1, b0, b1, b2, b3)                                      \
        FMA4(acc2, a2, b0, b1, b2, b3)                                      \
        FMA4(acc3, a3, b0, b1, b2, b3)                                      \
    }                                                                       \
    acc0.x = (acc0.x > 0.f) ? acc0.x : SLOPE * acc0.x;                      \
    acc0.y = (acc0.y > 0.f) ? acc0.y : SLOPE * acc0.y;                      \
    acc0.z = (acc0.z > 0.f) ? acc0.z : SLOPE * acc0.z;                      \
    acc0.w = (acc0.w > 0.f) ? acc0.w : SLOPE * acc0.w;                      \
    acc1.x = (acc1.x > 0.f) ? acc1.x : SLOPE * acc1.x;                      \
    acc1.y = (acc1.y > 0.f) ? acc1.y : SLOPE * acc1.y;                      \
    acc1.z = (acc1.z > 0.f) ? acc1.z : SLOPE * acc1.z;                      \
    acc1.w = (acc1.w > 0.f) ? acc1.w : SLOPE * acc1.w;                      \
    acc2.x = (acc2.x > 0.f) ? acc2.x : SLOPE * acc2.x;                      \
    acc2.y = (acc2.y > 0.f) ? acc2.y : SLOPE * acc2.y;                      \
    acc2.z = (acc2.z > 0.f) ? acc2.z : SLOPE * acc2.z;                      \
    acc2.w = (acc2.w > 0.f) ? acc2.w : SLOPE * acc2.w;                      \
    acc3.x = (acc3.x > 0.f) ? acc3.x : SLOPE * acc3.x;                      \
    acc3.y = (acc3.y > 0.f) ? acc3.y : SLOPE * acc3.y;                      \
    acc3.z = (acc3.z > 0.f) ? acc3.z : SLOPE * acc3.z;                      \
    acc3.w = (acc3.w > 0.f) ? acc3.w : SLOPE * acc3.w;

__global__ __launch_bounds__(256, 2) void sage_gemm(
    const float* __restrict__ mean, const float* __restrict__ h_in,
    float* __restrict__ h_out,
    const float* __restrict__ Wl, const float* __restrict__ bl,
    const float* __restrict__ Wr, int n) {
    GEMM_BODY()
    #define STORE_ROW(S, ACC)                                               \
        { int r = r0 + 16 * S;                                              \
          if (r < rows)                                                     \
              *(float4*)(h_out + (size_t)(base + r) * HD + j0) = ACC; }
    STORE_ROW(0, acc0)
    STORE_ROW(1, acc1)
    STORE_ROW(2, acc2)
    STORE_ROW(3, acc3)
    #undef STORE_ROW
}

__global__ __launch_bounds__(256, 2) void sage_gemm_out(
    const float* __restrict__ mean, const float* __restrict__ h_in,
    const float* __restrict__ Wl, const float* __restrict__ bl,
    const float* __restrict__ Wr,
    const float* __restrict__ Wout, const float* __restrict__ bout,
    float* __restrict__ out, int n) {
    GEMM_BODY(__shared__ float s_part[16][64];)
    const float4 w4 = *(const float4*)(Wout + j0);
    const int jg = t >> 4;
    s_part[jg][r0 +  0] = acc0.x * w4.x + acc0.y * w4.y + acc0.z * w4.z + acc0.w * w4.w;
    s_part[jg][r0 + 16] = acc1.x * w4.x + acc1.y * w4.y + acc1.z * w4.z + acc1.w * w4.w;
    s_part[jg][r0 + 32] = acc2.x * w4.x + acc2.y * w4.y + acc2.z * w4.z + acc2.w * w4.w;
    s_part[jg][r0 + 48] = acc3.x * w4.x + acc3.y * w4.y + acc3.z * w4.z + acc3.w * w4.w;
    __syncthreads();
    if (t < 64) {
        float sum = 0.f;
        #pragma unroll
        for (int g = 0; g < 16; ++g) sum += s_part[g][t];
        if (t < rows) out[base + t] = sum + bout[0];
    }
}

// ---------------------------------------------------------------------------

extern "C" void kernel_launch(void* const* d_in, const int* in_sizes, int n_in,
                              void* d_out, int out_size, void* d_ws, size_t ws_size,
                              hipStream_t stream) {
    const float* x   = (const float*)d_in[0];
    const int* ei    = (const int*)d_in[1];
    const float* Wl1 = (const float*)d_in[2];
    const float* bl1 = (const float*)d_in[3];
    const float* Wr1 = (const float*)d_in[4];
    const float* Wl2 = (const float*)d_in[5];
    const float* bl2 = (const float*)d_in[6];
    const float* Wr2 = (const float*)d_in[7];
    const float* Wl3 = (const float*)d_in[8];
    const float* bl3 = (const float*)d_in[9];
    const float* Wr3 = (const float*)d_in[10];
    const float* Wout = (const float*)d_in[11];
    const float* bout = (const float*)d_in[12];
    float* out = (float*)d_out;

    const int N = in_sizes[0] / HD;       // 50000
    const int E = in_sizes[1] / 2;        // 800000
    const int NB = (N + BNODES - 1) >> BSH;   // 782 buckets

    // Workspace layout — float4-accessed buffers first (16B alignment).
    float* hMean  = (float*)d_ws;                   // [N*64]
    float* hA     = hMean + (size_t)N * HD;         // [N*64]
    float* hB     = hA + (size_t)N * HD;            // [N*64]
    int* ebuf     = (int*)(hB + (size_t)N * HD);    // [E] packed src<<6|dstLow
    int* colidx   = ebuf + E;                       // [E] CSR
    int* rowptr   = colidx + E;                     // [N+1]
    float* invdeg = (float*)(rowptr + N + 1);       // [N]
    int* bsize    = (int*)(invdeg + N);             // [784]
    int* bbase    = bsize + 784;                    // [785]
    int* bcur     = bbase + 785;                    // [784]

    hipMemsetAsync(bsize, 0, 784 * sizeof(int), stream);

    hist_kernel<<<128, 256, 0, stream>>>(ei, bsize, E, NB);
    bscan_kernel<<<1, 256, 0, stream>>>(bsize, bbase, bcur, NB, E);
    part_kernel<<<(E + CHUNK - 1) / CHUNK, 256, 0, stream>>>(ei, bcur, ebuf, E, NB);
    bsort_kernel<<<NB, 256, 0, stream>>>(ebuf, bbase, colidx, rowptr, invdeg, N, E);

    const int agrid = 2048;               // 8192 waves, grid-stride over tiles
    const int ggrid = (N + 63) / 64;      // 782 tiles

    aggregate_kernel<<<agrid, 256, 0, stream>>>(x, hMean, rowptr, colidx, invdeg, N);
    sage_gemm<<<ggrid, 256, 0, stream>>>(hMean, x, hA, Wl1, bl1, Wr1, N);

    aggregate_kernel<<<agrid, 256, 0, stream>>>(hA, hMean, rowptr, colidx, invdeg, N);
    sage_gemm<<<ggrid, 256, 0, stream>>>(hMean, hA, hB, Wl2, bl2, Wr2, N);

    aggregate_kernel<<<agrid, 256, 0, stream>>>(hB, hMean, rowptr, colidx, invdeg, N);
    sage_gemm_out<<<ggrid, 256, 0, stream>>>(hMean, hB, Wl3, bl3, Wr3, Wout, bout, out, N);
}

// Round 9
// 273.179 us; speedup vs baseline: 4.4699x; 1.0332x over previous
//
#include <hip/hip_runtime.h>

#define HD 64
#define SLOPE 0.01f
#define BSH 6                    // 64 nodes per bucket
#define BNODES 64
#define CHUNK 8192               // edges per partition block

// ---------------------------------------------------------------------------
// Build v3 (R8-proven): bucket histogram -> scan -> localized partition ->
// per-bucket counting sort. ~8 MB write traffic vs naive fill's 53 MB.
// ---------------------------------------------------------------------------

__global__ __launch_bounds__(256) void hist_kernel(const int* __restrict__ ei,
                                                   int* __restrict__ bsize,
                                                   int E, int nb) {
    __shared__ int h[784];
    const int t = threadIdx.x;
    for (int i = t; i < nb; i += 256) h[i] = 0;
    __syncthreads();
    const int stride = gridDim.x * 256;
    for (int e = blockIdx.x * 256 + t; e < E; e += stride)
        atomicAdd(&h[ei[E + e] >> BSH], 1);
    __syncthreads();
    for (int i = t; i < nb; i += 256) {
        int v = h[i];
        if (v) atomicAdd(&bsize[i], v);
    }
}

__global__ __launch_bounds__(256) void bscan_kernel(const int* __restrict__ bsize,
                                                    int* __restrict__ bbase,
                                                    int* __restrict__ bcur,
                                                    int nb, int E) {
    __shared__ int wsum[4];
    const int t = threadIdx.x, lane = t & 63, wid = t >> 6;
    int v[4];
    int s = 0;
    #pragma unroll
    for (int j = 0; j < 4; ++j) {
        int i = t * 4 + j;
        v[j] = (i < nb) ? bsize[i] : 0;
        s += v[j];
    }
    int x = s;
    #pragma unroll
    for (int d = 1; d < 64; d <<= 1) { int y = __shfl_up(x, d, 64); if (lane >= d) x += y; }
    if (lane == 63) wsum[wid] = x;
    __syncthreads();
    if (wid == 0 && lane < 4) {
        int ws = wsum[lane], xs = ws;
        #pragma unroll
        for (int d = 1; d < 4; d <<= 1) { int y = __shfl_up(xs, d, 64); if (lane >= d) xs += y; }
        wsum[lane] = xs - ws;
    }
    __syncthreads();
    int base = wsum[wid] + (x - s);
    #pragma unroll
    for (int j = 0; j < 4; ++j) {
        int i = t * 4 + j;
        if (i < nb) { bbase[i] = base; bcur[i] = base; }
        base += v[j];
    }
    if (t == 0) bbase[nb] = E;
}

__global__ __launch_bounds__(256) void part_kernel(const int* __restrict__ ei,
                                                   int* __restrict__ bcur,
                                                   int* __restrict__ ebuf,
                                                   int E, int nb) {
    __shared__ int pk_s[CHUNK];
    __shared__ int mt_s[CHUNK];
    __shared__ int hist[784];
    __shared__ int sbase[784];
    const int t = threadIdx.x;
    const int c0 = blockIdx.x * CHUNK;
    const int cnt = min(CHUNK, E - c0);
    for (int i = t; i < nb; i += 256) hist[i] = 0;
    __syncthreads();
    for (int i = t; i < cnt; i += 256) {
        int src = ei[c0 + i];
        int dst = ei[E + c0 + i];
        int b = dst >> BSH;
        pk_s[i] = (src << BSH) | (dst & (BNODES - 1));
        int r = atomicAdd(&hist[b], 1);
        mt_s[i] = (b << 13) | r;           // rank < CHUNK = 2^13
    }
    __syncthreads();
    for (int b = t; b < nb; b += 256) {
        int h = hist[b];
        if (h) sbase[b] = atomicAdd(&bcur[b], h);
    }
    __syncthreads();
    for (int i = t; i < cnt; i += 256) {
        int m = mt_s[i];
        int b = m >> 13;
        ebuf[sbase[b] + (m & (CHUNK - 1))] = pk_s[i];
    }
}

__global__ __launch_bounds__(256) void bsort_kernel(const int* __restrict__ ebuf,
                                                    const int* __restrict__ bbase,
                                                    int* __restrict__ colidx,
                                                    int* __restrict__ rowptr,
                                                    float* __restrict__ invdeg,
                                                    int n, int E) {
    __shared__ int cnt[BNODES];
    const int b = blockIdx.x;
    const int t = threadIdx.x;
    const int ebeg = bbase[b], eend = bbase[b + 1];
    if (t < BNODES) cnt[t] = 0;
    __syncthreads();
    for (int k = ebeg + t; k < eend; k += 256)
        atomicAdd(&cnt[ebuf[k] & (BNODES - 1)], 1);
    __syncthreads();
    if (t < BNODES) {                      // wave 0: scan the 64 counters
        int v = cnt[t];
        int x = v;
        #pragma unroll
        for (int d = 1; d < 64; d <<= 1) { int y = __shfl_up(x, d, 64); if (t >= d) x += y; }
        int excl = x - v;
        int node = b * BNODES + t;
        if (node < n) {
            rowptr[node] = ebeg + excl;
            invdeg[node] = 1.0f / (float)((v > 1) ? v : 1);
        }
        cnt[t] = excl;                     // becomes the running cursor
    }
    if (b == 0 && t == 0) rowptr[n] = E;
    __syncthreads();
    for (int k = ebeg + t; k < eend; k += 256) {
        int p = ebuf[k];
        int r = atomicAdd(&cnt[p & (BNODES - 1)], 1);
        colidx[ebeg + r] = p >> BSH;
    }
}

// ---------------------------------------------------------------------------
// fp32 -> fp16 shadow copy (round-to-nearest). Grid-stride, 8 elems/thread.
// ---------------------------------------------------------------------------

__global__ __launch_bounds__(256) void tohalf_kernel(const float* __restrict__ in,
                                                     _Float16* __restrict__ out,
                                                     int n64) {        // total elems
    int i = (blockIdx.x * 256 + threadIdx.x) * 8;
    if (i >= n64) return;
    float4 a = *(const float4*)(in + i);
    float4 b = *(const float4*)(in + i + 4);
    _Float16 o[8] = {(_Float16)a.x, (_Float16)a.y, (_Float16)a.z, (_Float16)a.w,
                     (_Float16)b.x, (_Float16)b.y, (_Float16)b.z, (_Float16)b.w};
    *(float4*)(out + i) = *(float4*)o;     // 16B store of 8 halves
}

// ---------------------------------------------------------------------------
// Aggregation v4: 4 nodes per wave, one 16-lane group per node, gathering
// from the fp16 shadow (128B/row instead of 256B -> halves the random-line
// fabric traffic the R8 counters showed to be the bound). Accumulation fp32.
// All __shfl executed by ALL lanes (R3 lesson).
// ---------------------------------------------------------------------------

__global__ __launch_bounds__(256) void aggregate_kernel(
    const _Float16* __restrict__ h16, float* __restrict__ mean_out,
    const int* __restrict__ rowptr, const int* __restrict__ colidx,
    const float* __restrict__ inv_deg, int n) {
    const int lane = threadIdx.x & 63;
    const int wslot = threadIdx.x >> 6;
    const int g = lane >> 4;     // node slot within tile (0..3)
    const int c4 = lane & 15;    // 4-channel chunk of the 64-ch row
    const float2* __restrict__ h2 = (const float2*)h16;   // row = 16 float2
    float4* __restrict__ m4 = (float4*)mean_out;

    const int ntiles = gridDim.x * 4;
    const int ntile_tot = (n + 3) >> 2;

    for (int tile = blockIdx.x * 4 + wslot; tile < ntile_tot; tile += ntiles) {
        const int node = tile * 4 + g;
        const bool valid = node < n;
        int beg = 0, end = 0; float idg = 0.f;
        if (valid) {
            beg = rowptr[node];
            end = rowptr[node + 1];
            idg = inv_deg[node];
        }
        const int deg = end - beg;

        int md = deg;
        md = max(md, __shfl_xor(md, 16, 64));
        md = max(md, __shfl_xor(md, 32, 64));

        float4 acc = {0.f, 0.f, 0.f, 0.f};
        for (int t0 = 0; t0 < md; t0 += 16) {
            int ci = 0;
            const int off = beg + t0 + c4;
            if (off < end) ci = colidx[off];    // 4 coalesced 64B segments
            const int jmax = (md - t0 < 16) ? (md - t0) : 16;
            #pragma unroll 4
            for (int j = 0; j < 16; ++j) {
                if (j >= jmax) break;                    // wave-uniform
                int idx = __shfl(ci, g * 16 + j, 64);    // all lanes execute
                if (t0 + j < deg) {                      // group-uniform
                    float2 raw = h2[(size_t)idx * 16 + c4];   // 8B = 4 halves
                    const _Float16* hp = (const _Float16*)&raw;
                    acc.x += (float)hp[0];
                    acc.y += (float)hp[1];
                    acc.z += (float)hp[2];
                    acc.w += (float)hp[3];
                }
            }
        }
        if (valid) {
            float4 o = {acc.x * idg, acc.y * idg, acc.z * idg, acc.w * idg};
            m4[(size_t)node * 16 + c4] = o;    // wave stores 4 rows = 1KB
        }
    }
}

// ---------------------------------------------------------------------------
// Dense: out = leaky(mean @ Wl + bl + self @ Wr), 64x64 tile per block,
// 4x4 register blocking per thread — constant-indexed frags, no spill.
// sage_gemm additionally stores the fp16 shadow for the next layer's gather.
// ---------------------------------------------------------------------------

#define FMA4(acc, am, b0, b1, b2, b3)                                  \
    acc.x += am.x * b0.x + am.y * b1.x + am.z * b2.x + am.w * b3.x;    \
    acc.y += am.x * b0.y + am.y * b1.y + am.z * b2.y + am.w * b3.y;    \
    acc.z += am.x * b0.z + am.y * b1.z + am.z * b2.z + am.w * b3.z;    \
    acc.w += am.x * b0.w + am.y * b1.w + am.z * b2.w + am.w * b3.w;

#define GEMM_BODY(EXTRA_SHARED)                                             \
    __shared__ float sA[64 * 68];                                           \
    __shared__ float sS[64 * 68];                                           \
    __shared__ float sWl[64 * 64];                                          \
    __shared__ float sWr[64 * 64];                                          \
    EXTRA_SHARED                                                            \
    const int t = threadIdx.x;                                              \
    const int r0 = t & 15;                                                  \
    const int j0 = (t >> 4) * 4;                                            \
    const int base = blockIdx.x * 64;                                       \
    const int rows = min(64, n - base);                                     \
    const float4* __restrict__ m4 = (const float4*)mean;                    \
    const float4* __restrict__ h4 = (const float4*)h_in;                    \
    _Pragma("unroll")                                                       \
    for (int idx = 0; idx < 4; ++idx) {                                     \
        int i = t + idx * 256;                                              \
        ((float4*)sWl)[i] = ((const float4*)Wl)[i];                         \
        ((float4*)sWr)[i] = ((const float4*)Wr)[i];                         \
    }                                                                       \
    _Pragma("unroll")                                                       \
    for (int idx = 0; idx < 4; ++idx) {                                     \
        int i = t + idx * 256;                                              \
        int r = i >> 4, c4 = i & 15;                                        \
        float4 va = {0.f, 0.f, 0.f, 0.f}, vs = {0.f, 0.f, 0.f, 0.f};        \
        if (r < rows) {                                                     \
            va = m4[(size_t)(base + r) * 16 + c4];                          \
            vs = h4[(size_t)(base + r) * 16 + c4];                          \
        }                                                                   \
        *(float4*)(sA + r * 68 + 4 * c4) = va;                              \
        *(float4*)(sS + r * 68 + 4 * c4) = vs;                              \
    }                                                                       \
    __syncthreads();                                                        \
    const float4 bias = *(const float4*)(bl + j0);                          \
    float4 acc0 = bias, acc1 = bias, acc2 = bias, acc3 = bias;              \
    _Pragma("unroll 2")                                                     \
    for (int k4 = 0; k4 < 16; ++k4) {                                       \
        float4 b0 = *(const float4*)(sWl + (4 * k4 + 0) * 64 + j0);         \
        float4 b1 = *(const float4*)(sWl + (4 * k4 + 1) * 64 + j0);         \
        float4 b2 = *(const float4*)(sWl + (4 * k4 + 2) * 64 + j0);         \
        float4 b3 = *(const float4*)(sWl + (4 * k4 + 3) * 64 + j0);         \
        float4 a0 = *(const float4*)(sA + (r0 +  0) * 68 + 4 * k4);         \
        float4 a1 = *(const float4*)(sA + (r0 + 16) * 68 + 4 * k4);         \
        float4 a2 = *(const float4*)(sA + (r0 + 32) * 68 + 4 * k4);         \
        float4 a3 = *(const float4*)(sA + (r0 + 48) * 68 + 4 * k4);         \
        FMA4(acc0, a0, b0, b1, b2, b3)                                      \
        FMA4(acc1, a1, b0, b1, b2, b3)                                      \
        FMA4(acc2, a2, b0, b1, b2, b3)                                      \
        FMA4(acc3, a3, b0, b1, b2, b3)                                      \
        b0 = *(const float4*)(sWr + (4 * k4 + 0) * 64 + j0);                \
        b1 = *(const float4*)(sWr + (4 * k4 + 1) * 64 + j0);                \
        b2 = *(const float4*)(sWr + (4 * k4 + 2) * 64 + j0);                \
        b3 = *(const float4*)(sWr + (4 * k4 + 3) * 64 + j0);                \
        a0 = *(const float4*)(sS + (r0 +  0) * 68 + 4 * k4);                \
        a1 = *(const float4*)(sS + (r0 + 16) * 68 + 4 * k4);                \
        a2 = *(const float4*)(sS + (r0 + 32) * 68 + 4 * k4);                \
        a3 = *(const float4*)(sS + (r0 + 48) * 68 + 4 * k4);                \
        FMA4(acc0, a0, b0, b1, b2, b3)                                      \
        FMA4(acc1, a1, b0, b1, b2, b3)                                      \
        FMA4(acc2, a2, b0, b1, b2, b3)                                      \
        FMA4(acc3, a3, b0, b1, b2, b3)                                      \
    }                                                                       \
    acc0.x = (acc0.x > 0.f) ? acc0.x : SLOPE * acc0.x;                      \
    acc0.y = (acc0.y > 0.f) ? acc0.y : SLOPE * acc0.y;                      \
    acc0.z = (acc0.z > 0.f) ? acc0.z : SLOPE * acc0.z;                      \
    acc0.w = (acc0.w > 0.f) ? acc0.w : SLOPE * acc0.w;                      \
    acc1.x = (acc1.x > 0.f) ? acc1.x : SLOPE * acc1.x;                      \
    acc1.y = (acc1.y > 0.f) ? acc1.y : SLOPE * acc1.y;                      \
    acc1.z = (acc1.z > 0.f) ? acc1.z : SLOPE * acc1.z;                      \
    acc1.w = (acc1.w > 0.f) ? acc1.w : SLOPE * acc1.w;                      \
    acc2.x = (acc2.x > 0.f) ? acc2.x : SLOPE * acc2.x;                      \
    acc2.y = (acc2.y > 0.f) ? acc2.y : SLOPE * acc2.y;                      \
    acc2.z = (acc2.z > 0.f) ? acc2.z : SLOPE * acc2.z;                      \
    acc2.w = (acc2.w > 0.f) ? acc2.w : SLOPE * acc2.w;                      \
    acc3.x = (acc3.x > 0.f) ? acc3.x : SLOPE * acc3.x;                      \
    acc3.y = (acc3.y > 0.f) ? acc3.y : SLOPE * acc3.y;                      \
    acc3.z = (acc3.z > 0.f) ? acc3.z : SLOPE * acc3.z;                      \
    acc3.w = (acc3.w > 0.f) ? acc3.w : SLOPE * acc3.w;

__global__ __launch_bounds__(256, 2) void sage_gemm(
    const float* __restrict__ mean, const float* __restrict__ h_in,
    float* __restrict__ h_out, _Float16* __restrict__ h16_out,
    const float* __restrict__ Wl, const float* __restrict__ bl,
    const float* __restrict__ Wr, int n) {
    GEMM_BODY()
    #define STORE_ROW(S, ACC)                                               \
        { int r = r0 + 16 * S;                                              \
          if (r < rows) {                                                   \
              *(float4*)(h_out + (size_t)(base + r) * HD + j0) = ACC;       \
              _Float16 o[4] = {(_Float16)ACC.x, (_Float16)ACC.y,            \
                               (_Float16)ACC.z, (_Float16)ACC.w};           \
              *(float2*)(h16_out + (size_t)(base + r) * HD + j0)            \
                  = *(float2*)o;                                            \
          } }
    STORE_ROW(0, acc0)
    STORE_ROW(1, acc1)
    STORE_ROW(2, acc2)
    STORE_ROW(3, acc3)
    #undef STORE_ROW
}

__global__ __launch_bounds__(256, 2) void sage_gemm_out(
    const float* __restrict__ mean, const float* __restrict__ h_in,
    const float* __restrict__ Wl, const float* __restrict__ bl,
    const float* __restrict__ Wr,
    const float* __restrict__ Wout, const float* __restrict__ bout,
    float* __restrict__ out, int n) {
    GEMM_BODY(__shared__ float s_part[16][64];)
    const float4 w4 = *(const float4*)(Wout + j0);
    const int jg = t >> 4;
    s_part[jg][r0 +  0] = acc0.x * w4.x + acc0.y * w4.y + acc0.z * w4.z + acc0.w * w4.w;
    s_part[jg][r0 + 16] = acc1.x * w4.x + acc1.y * w4.y + acc1.z * w4.z + acc1.w * w4.w;
    s_part[jg][r0 + 32] = acc2.x * w4.x + acc2.y * w4.y + acc2.z * w4.z + acc2.w * w4.w;
    s_part[jg][r0 + 48] = acc3.x * w4.x + acc3.y * w4.y + acc3.z * w4.z + acc3.w * w4.w;
    __syncthreads();
    if (t < 64) {
        float sum = 0.f;
        #pragma unroll
        for (int g = 0; g < 16; ++g) sum += s_part[g][t];
        if (t < rows) out[base + t] = sum + bout[0];
    }
}

// ---------------------------------------------------------------------------

extern "C" void kernel_launch(void* const* d_in, const int* in_sizes, int n_in,
                              void* d_out, int out_size, void* d_ws, size_t ws_size,
                              hipStream_t stream) {
    const float* x   = (const float*)d_in[0];
    const int* ei    = (const int*)d_in[1];
    const float* Wl1 = (const float*)d_in[2];
    const float* bl1 = (const float*)d_in[3];
    const float* Wr1 = (const float*)d_in[4];
    const float* Wl2 = (const float*)d_in[5];
    const float* bl2 = (const float*)d_in[6];
    const float* Wr2 = (const float*)d_in[7];
    const float* Wl3 = (const float*)d_in[8];
    const float* bl3 = (const float*)d_in[9];
    const float* Wr3 = (const float*)d_in[10];
    const float* Wout = (const float*)d_in[11];
    const float* bout = (const float*)d_in[12];
    float* out = (float*)d_out;

    const int N = in_sizes[0] / HD;       // 50000
    const int E = in_sizes[1] / 2;        // 800000
    const int NB = (N + BNODES - 1) >> BSH;   // 782 buckets

    // Workspace layout — float4-accessed buffers first (16B alignment).
    float* hMean  = (float*)d_ws;                    // [N*64] f32
    float* hA     = hMean + (size_t)N * HD;          // [N*64] f32
    float* hB     = hA + (size_t)N * HD;             // [N*64] f32
    _Float16* hHalf = (_Float16*)(hB + (size_t)N * HD);  // [N*64] f16 shadow
    int* ebuf     = (int*)(hHalf + (size_t)N * HD);  // [E] packed src<<6|dstLow
    int* colidx   = ebuf + E;                        // [E] CSR
    int* rowptr   = colidx + E;                      // [N+1]
    float* invdeg = (float*)(rowptr + N + 1);        // [N]
    int* bsize    = (int*)(invdeg + N);              // [784]
    int* bbase    = bsize + 784;                     // [785]
    int* bcur     = bbase + 785;                     // [784]

    hipMemsetAsync(bsize, 0, 784 * sizeof(int), stream);

    hist_kernel<<<128, 256, 0, stream>>>(ei, bsize, E, NB);
    bscan_kernel<<<1, 256, 0, stream>>>(bsize, bbase, bcur, NB, E);
    part_kernel<<<(E + CHUNK - 1) / CHUNK, 256, 0, stream>>>(ei, bcur, ebuf, E, NB);
    bsort_kernel<<<NB, 256, 0, stream>>>(ebuf, bbase, colidx, rowptr, invdeg, N, E);

    const int n64 = N * HD;
    tohalf_kernel<<<(n64 / 8 + 255) / 256, 256, 0, stream>>>(x, hHalf, n64);

    const int agrid = 2048;               // 8192 waves, grid-stride over tiles
    const int ggrid = (N + 63) / 64;      // 782 tiles

    aggregate_kernel<<<agrid, 256, 0, stream>>>(hHalf, hMean, rowptr, colidx, invdeg, N);
    sage_gemm<<<ggrid, 256, 0, stream>>>(hMean, x, hA, hHalf, Wl1, bl1, Wr1, N);

    aggregate_kernel<<<agrid, 256, 0, stream>>>(hHalf, hMean, rowptr, colidx, invdeg, N);
    sage_gemm<<<ggrid, 256, 0, stream>>>(hMean, hA, hB, hHalf, Wl2, bl2, Wr2, N);

    aggregate_kernel<<<agrid, 256, 0, stream>>>(hHalf, hMean, rowptr, colidx, invdeg, N);
    sage_gemm_out<<<ggrid, 256, 0, stream>>>(hMean, hB, Wl3, bl3, Wr3, Wout, bout, out, N);
}

// Round 10
// 242.597 us; speedup vs baseline: 5.0334x; 1.1261x over previous
//
#include <hip/hip_runtime.h>

#define HD 64
#define SLOPE 0.01f
#define BSH 6                    // 64 nodes per bucket
#define BNODES 64
#define CHUNK 4096               // edges per partition block (LDS 38KB -> 4 blk/CU)

// ---------------------------------------------------------------------------
// Build v3 (R8-proven): bucket histogram -> scan -> localized partition ->
// per-bucket counting sort. ~8 MB write traffic vs naive fill's 53 MB.
// ---------------------------------------------------------------------------

__global__ __launch_bounds__(256) void hist_kernel(const int* __restrict__ ei,
                                                   int* __restrict__ bsize,
                                                   int E, int nb) {
    __shared__ int h[784];
    const int t = threadIdx.x;
    for (int i = t; i < nb; i += 256) h[i] = 0;
    __syncthreads();
    const int stride = gridDim.x * 256;
    for (int e = blockIdx.x * 256 + t; e < E; e += stride)
        atomicAdd(&h[ei[E + e] >> BSH], 1);
    __syncthreads();
    for (int i = t; i < nb; i += 256) {
        int v = h[i];
        if (v) atomicAdd(&bsize[i], v);
    }
}

__global__ __launch_bounds__(256) void bscan_kernel(const int* __restrict__ bsize,
                                                    int* __restrict__ bbase,
                                                    int* __restrict__ bcur,
                                                    int nb, int E) {
    __shared__ int wsum[4];
    const int t = threadIdx.x, lane = t & 63, wid = t >> 6;
    int v[4];
    int s = 0;
    #pragma unroll
    for (int j = 0; j < 4; ++j) {
        int i = t * 4 + j;
        v[j] = (i < nb) ? bsize[i] : 0;
        s += v[j];
    }
    int x = s;
    #pragma unroll
    for (int d = 1; d < 64; d <<= 1) { int y = __shfl_up(x, d, 64); if (lane >= d) x += y; }
    if (lane == 63) wsum[wid] = x;
    __syncthreads();
    if (wid == 0 && lane < 4) {
        int ws = wsum[lane], xs = ws;
        #pragma unroll
        for (int d = 1; d < 4; d <<= 1) { int y = __shfl_up(xs, d, 64); if (lane >= d) xs += y; }
        wsum[lane] = xs - ws;
    }
    __syncthreads();
    int base = wsum[wid] + (x - s);
    #pragma unroll
    for (int j = 0; j < 4; ++j) {
        int i = t * 4 + j;
        if (i < nb) { bbase[i] = base; bcur[i] = base; }
        base += v[j];
    }
    if (t == 0) bbase[nb] = E;
}

__global__ __launch_bounds__(256) void part_kernel(const int* __restrict__ ei,
                                                   int* __restrict__ bcur,
                                                   int* __restrict__ ebuf,
                                                   int E, int nb) {
    __shared__ int pk_s[CHUNK];
    __shared__ int mt_s[CHUNK];
    __shared__ int hist[784];
    __shared__ int sbase[784];
    const int t = threadIdx.x;
    const int c0 = blockIdx.x * CHUNK;
    const int cnt = min(CHUNK, E - c0);
    for (int i = t; i < nb; i += 256) hist[i] = 0;
    __syncthreads();
    for (int i = t; i < cnt; i += 256) {
        int src = ei[c0 + i];
        int dst = ei[E + c0 + i];
        int b = dst >> BSH;
        pk_s[i] = (src << BSH) | (dst & (BNODES - 1));
        int r = atomicAdd(&hist[b], 1);
        mt_s[i] = (b << 12) | r;           // rank < CHUNK = 2^12
    }
    __syncthreads();
    for (int b = t; b < nb; b += 256) {
        int h = hist[b];
        if (h) sbase[b] = atomicAdd(&bcur[b], h);
    }
    __syncthreads();
    for (int i = t; i < cnt; i += 256) {
        int m = mt_s[i];
        int b = m >> 12;
        ebuf[sbase[b] + (m & (CHUNK - 1))] = pk_s[i];
    }
}

__global__ __launch_bounds__(256) void bsort_kernel(const int* __restrict__ ebuf,
                                                    const int* __restrict__ bbase,
                                                    int* __restrict__ colidx,
                                                    int* __restrict__ rowptr,
                                                    float* __restrict__ invdeg,
                                                    int n, int E) {
    __shared__ int cnt[BNODES];
    const int b = blockIdx.x;
    const int t = threadIdx.x;
    const int ebeg = bbase[b], eend = bbase[b + 1];
    if (t < BNODES) cnt[t] = 0;
    __syncthreads();
    for (int k = ebeg + t; k < eend; k += 256)
        atomicAdd(&cnt[ebuf[k] & (BNODES - 1)], 1);
    __syncthreads();
    if (t < BNODES) {                      // wave 0: scan the 64 counters
        int v = cnt[t];
        int x = v;
        #pragma unroll
        for (int d = 1; d < 64; d <<= 1) { int y = __shfl_up(x, d, 64); if (t >= d) x += y; }
        int excl = x - v;
        int node = b * BNODES + t;
        if (node < n) {
            rowptr[node] = ebeg + excl;
            invdeg[node] = 1.0f / (float)((v > 1) ? v : 1);
        }
        cnt[t] = excl;                     // becomes the running cursor
    }
    if (b == 0 && t == 0) rowptr[n] = E;
    __syncthreads();
    for (int k = ebeg + t; k < eend; k += 256) {
        int p = ebuf[k];
        int r = atomicAdd(&cnt[p & (BNODES - 1)], 1);
        colidx[ebeg + r] = p >> BSH;
    }
}

// ---------------------------------------------------------------------------
// fp32 -> fp16 shadow copy (round-to-nearest). Grid-stride, 8 elems/thread.
// ---------------------------------------------------------------------------

__global__ __launch_bounds__(256) void tohalf_kernel(const float* __restrict__ in,
                                                     _Float16* __restrict__ out,
                                                     int n64) {
    int i = (blockIdx.x * 256 + threadIdx.x) * 8;
    if (i >= n64) return;
    float4 a = *(const float4*)(in + i);
    float4 b = *(const float4*)(in + i + 4);
    _Float16 o[8] = {(_Float16)a.x, (_Float16)a.y, (_Float16)a.z, (_Float16)a.w,
                     (_Float16)b.x, (_Float16)b.y, (_Float16)b.z, (_Float16)b.w};
    *(float4*)(out + i) = *(float4*)o;     // 16B store of 8 halves
}

// ---------------------------------------------------------------------------
// Aggregation v5: 4 nodes per wave, 16-lane group per node, fp16 gather.
// Inner loop restructured for ILP: batches of 8 neighbors behind a
// WAVE-UNIFORM guard (shfl-safe), unconditional loads with clamp-to-row-0
// addressing + select-multiplier accumulate -> 8 gathers in flight with no
// per-neighbor branches/waits (R9's loop kept only ~4 due to the break).
// ---------------------------------------------------------------------------

__global__ __launch_bounds__(256) void aggregate_kernel(
    const _Float16* __restrict__ h16, float* __restrict__ mean_out,
    const int* __restrict__ rowptr, const int* __restrict__ colidx,
    const float* __restrict__ inv_deg, int n) {
    const int lane = threadIdx.x & 63;
    const int wslot = threadIdx.x >> 6;
    const int g = lane >> 4;     // node slot within tile (0..3)
    const int c4 = lane & 15;    // 4-channel chunk of the 64-ch row
    const float2* __restrict__ h2 = (const float2*)h16;   // row = 16 float2
    float4* __restrict__ m4 = (float4*)mean_out;

    const int ntiles = gridDim.x * 4;
    const int ntile_tot = (n + 3) >> 2;

    for (int tile = blockIdx.x * 4 + wslot; tile < ntile_tot; tile += ntiles) {
        const int node = tile * 4 + g;
        const bool valid = node < n;
        int beg = 0, end = 0; float idg = 0.f;
        if (valid) {
            beg = rowptr[node];
            end = rowptr[node + 1];
            idg = inv_deg[node];
        }
        const int deg = end - beg;

        int md = deg;                              // wave-uniform max degree
        md = max(md, __shfl_xor(md, 16, 64));
        md = max(md, __shfl_xor(md, 32, 64));

        float4 acc = {0.f, 0.f, 0.f, 0.f};
        for (int t0 = 0; t0 < md; t0 += 16) {
            const int off = beg + t0 + c4;
            int ci = (off < end) ? colidx[off] : 0;

            #pragma unroll
            for (int half = 0; half < 2; ++half) {
                if (t0 + half * 8 >= md) break;    // wave-uniform guard
                int idx[8];
                #pragma unroll
                for (int k = 0; k < 8; ++k)        // 8 independent bpermutes
                    idx[k] = __shfl(ci, g * 16 + half * 8 + k, 64);
                float2 vv[8];
                float sel[8];
                #pragma unroll
                for (int k = 0; k < 8; ++k) {      // 8 unconditional loads
                    const bool p = (t0 + half * 8 + k) < deg;   // group-uniform
                    const int safe = p ? idx[k] : 0;            // row 0 = hot
                    sel[k] = p ? 1.0f : 0.0f;
                    vv[k] = h2[(size_t)safe * 16 + c4];
                }
                #pragma unroll
                for (int k = 0; k < 8; ++k) {
                    const _Float16* hp = (const _Float16*)&vv[k];
                    acc.x += sel[k] * (float)hp[0];
                    acc.y += sel[k] * (float)hp[1];
                    acc.z += sel[k] * (float)hp[2];
                    acc.w += sel[k] * (float)hp[3];
                }
            }
        }
        if (valid) {
            float4 o = {acc.x * idg, acc.y * idg, acc.z * idg, acc.w * idg};
            m4[(size_t)node * 16 + c4] = o;    // wave stores 4 rows = 1KB
        }
    }
}

// ---------------------------------------------------------------------------
// Dense: out = leaky(mean @ Wl + bl + self @ Wr), 64x64 tile per block,
// 4x4 register blocking per thread — constant-indexed frags, no spill.
// sage_gemm additionally stores the fp16 shadow for the next layer's gather.
// ---------------------------------------------------------------------------

#define FMA4(acc, am, b0, b1, b2, b3)                                  \
    acc.x += am.x * b0.x + am.y * b1.x + am.z * b2.x + am.w * b3.x;    \
    acc.y += am.x * b0.y + am.y * b1.y + am.z * b2.y + am.w * b3.y;    \
    acc.z += am.x * b0.z + am.y * b1.z + am.z * b2.z + am.w * b3.z;    \
    acc.w += am.x * b0.w + am.y * b1.w + am.z * b2.w + am.w * b3.w;

#define GEMM_BODY(EXTRA_SHARED)                                             \
    __shared__ float sA[64 * 68];                                           \
    __shared__ float sS[64 * 68];                                           \
    __shared__ float sWl[64 * 64];                                          \
    __shared__ float sWr[64 * 64];                                          \
    EXTRA_SHARED                                                            \
    const int t = threadIdx.x;                                              \
    const int r0 = t & 15;                                                  \
    const int j0 = (t >> 4) * 4;                                            \
    const int base = blockIdx.x * 64;                                       \
    const int rows = min(64, n - base);                                     \
    const float4* __restrict__ m4 = (const float4*)mean;                    \
    const float4* __restrict__ h4 = (const float4*)h_in;                    \
    _Pragma("unroll")                                                       \
    for (int idx = 0; idx < 4; ++idx) {                                     \
        int i = t + idx * 256;                                              \
        ((float4*)sWl)[i] = ((const float4*)Wl)[i];                         \
        ((float4*)sWr)[i] = ((const float4*)Wr)[i];                         \
    }                                                                       \
    _Pragma("unroll")                                                       \
    for (int idx = 0; idx < 4; ++idx) {                                     \
        int i = t + idx * 256;                                              \
        int r = i >> 4, c4 = i & 15;                                        \
        float4 va = {0.f, 0.f, 0.f, 0.f}, vs = {0.f, 0.f, 0.f, 0.f};        \
        if (r < rows) {                                                     \
            va = m4[(size_t)(base + r) * 16 + c4];                          \
            vs = h4[(size_t)(base + r) * 16 + c4];                          \
        }                                                                   \
        *(float4*)(sA + r * 68 + 4 * c4) = va;                              \
        *(float4*)(sS + r * 68 + 4 * c4) = vs;                              \
    }                                                                       \
    __syncthreads();                                                        \
    const float4 bias = *(const float4*)(bl + j0);                          \
    float4 acc0 = bias, acc1 = bias, acc2 = bias, acc3 = bias;              \
    _Pragma("unroll 2")                                                     \
    for (int k4 = 0; k4 < 16; ++k4) {                                       \
        float4 b0 = *(const float4*)(sWl + (4 * k4 + 0) * 64 + j0);         \
        float4 b1 = *(const float4*)(sWl + (4 * k4 + 1) * 64 + j0);         \
        float4 b2 = *(const float4*)(sWl + (4 * k4 + 2) * 64 + j0);         \
        float4 b3 = *(const float4*)(sWl + (4 * k4 + 3) * 64 + j0);         \
        float4 a0 = *(const float4*)(sA + (r0 +  0) * 68 + 4 * k4);         \
        float4 a1 = *(const float4*)(sA + (r0 + 16) * 68 + 4 * k4);         \
        float4 a2 = *(const float4*)(sA + (r0 + 32) * 68 + 4 * k4);         \
        float4 a3 = *(const float4*)(sA + (r0 + 48) * 68 + 4 * k4);         \
        FMA4(acc0, a0, b0, b1, b2, b3)                                      \
        FMA4(acc1, a1, b0, b1, b2, b3)                                      \
        FMA4(acc2, a2, b0, b1, b2, b3)                                      \
        FMA4(acc3, a3, b0, b1, b2, b3)                                      \
        b0 = *(const float4*)(sWr + (4 * k4 + 0) * 64 + j0);                \
        b1 = *(const float4*)(sWr + (4 * k4 + 1) * 64 + j0);                \
        b2 = *(const float4*)(sWr + (4 * k4 + 2) * 64 + j0);                \
        b3 = *(const float4*)(sWr + (4 * k4 + 3) * 64 + j0);                \
        a0 = *(const float4*)(sS + (r0 +  0) * 68 + 4 * k4);                \
        a1 = *(const float4*)(sS + (r0 + 16) * 68 + 4 * k4);                \
        a2 = *(const float4*)(sS + (r0 + 32) * 68 + 4 * k4);                \
        a3 = *(const float4*)(sS + (r0 + 48) * 68 + 4 * k4);                \
        FMA4(acc0, a0, b0, b1, b2, b3)                                      \
        FMA4(acc1, a1, b0, b1, b2, b3)                                      \
        FMA4(acc2, a2, b0, b1, b2, b3)                                      \
        FMA4(acc3, a3, b0, b1, b2, b3)                                      \
    }                                                                       \
    acc0.x = (acc0.x > 0.f) ? acc0.x : SLOPE * acc0.x;                      \
    acc0.y = (acc0.y > 0.f) ? acc0.y : SLOPE * acc0.y;                      \
    acc0.z = (acc0.z > 0.f) ? acc0.z : SLOPE * acc0.z;                      \
    acc0.w = (acc0.w > 0.f) ? acc0.w : SLOPE * acc0.w;                      \
    acc1.x = (acc1.x > 0.f) ? acc1.x : SLOPE * acc1.x;                      \
    acc1.y = (acc1.y > 0.f) ? acc1.y : SLOPE * acc1.y;                      \
    acc1.z = (acc1.z > 0.f) ? acc1.z : SLOPE * acc1.z;                      \
    acc1.w = (acc1.w > 0.f) ? acc1.w : SLOPE * acc1.w;                      \
    acc2.x = (acc2.x > 0.f) ? acc2.x : SLOPE * acc2.x;                      \
    acc2.y = (acc2.y > 0.f) ? acc2.y : SLOPE * acc2.y;                      \
    acc2.z = (acc2.z > 0.f) ? acc2.z : SLOPE * acc2.z;                      \
    acc2.w = (acc2.w > 0.f) ? acc2.w : SLOPE * acc2.w;                      \
    acc3.x = (acc3.x > 0.f) ? acc3.x : SLOPE * acc3.x;                      \
    acc3.y = (acc3.y > 0.f) ? acc3.y : SLOPE * acc3.y;                      \
    acc3.z = (acc3.z > 0.f) ? acc3.z : SLOPE * acc3.z;                      \
    acc3.w = (acc3.w > 0.f) ? acc3.w : SLOPE * acc3.w;

__global__ __launch_bounds__(256, 2) void sage_gemm(
    const float* __restrict__ mean, const float* __restrict__ h_in,
    float* __restrict__ h_out, _Float16* __restrict__ h16_out,
    const float* __restrict__ Wl, const float* __restrict__ bl,
    const float* __restrict__ Wr, int n) {
    GEMM_BODY()
    #define STORE_ROW(S, ACC)                                               \
        { int r = r0 + 16 * S;                                              \
          if (r < rows) {                                                   \
              *(float4*)(h_out + (size_t)(base + r) * HD + j0) = ACC;       \
              _Float16 o[4] = {(_Float16)ACC.x, (_Float16)ACC.y,            \
                               (_Float16)ACC.z, (_Float16)ACC.w};           \
              *(float2*)(h16_out + (size_t)(base + r) * HD + j0)            \
                  = *(float2*)o;                                            \
          } }
    STORE_ROW(0, acc0)
    STORE_ROW(1, acc1)
    STORE_ROW(2, acc2)
    STORE_ROW(3, acc3)
    #undef STORE_ROW
}

__global__ __launch_bounds__(256, 2) void sage_gemm_out(
    const float* __restrict__ mean, const float* __restrict__ h_in,
    const float* __restrict__ Wl, const float* __restrict__ bl,
    const float* __restrict__ Wr,
    const float* __restrict__ Wout, const float* __restrict__ bout,
    float* __restrict__ out, int n) {
    GEMM_BODY(__shared__ float s_part[16][64];)
    const float4 w4 = *(const float4*)(Wout + j0);
    const int jg = t >> 4;
    s_part[jg][r0 +  0] = acc0.x * w4.x + acc0.y * w4.y + acc0.z * w4.z + acc0.w * w4.w;
    s_part[jg][r0 + 16] = acc1.x * w4.x + acc1.y * w4.y + acc1.z * w4.z + acc1.w * w4.w;
    s_part[jg][r0 + 32] = acc2.x * w4.x + acc2.y * w4.y + acc2.z * w4.z + acc2.w * w4.w;
    s_part[jg][r0 + 48] = acc3.x * w4.x + acc3.y * w4.y + acc3.z * w4.z + acc3.w * w4.w;
    __syncthreads();
    if (t < 64) {
        float sum = 0.f;
        #pragma unroll
        for (int g = 0; g < 16; ++g) sum += s_part[g][t];
        if (t < rows) out[base + t] = sum + bout[0];
    }
}

// ---------------------------------------------------------------------------

extern "C" void kernel_launch(void* const* d_in, const int* in_sizes, int n_in,
                              void* d_out, int out_size, void* d_ws, size_t ws_size,
                              hipStream_t stream) {
    const float* x   = (const float*)d_in[0];
    const int* ei    = (const int*)d_in[1];
    const float* Wl1 = (const float*)d_in[2];
    const float* bl1 = (const float*)d_in[3];
    const float* Wr1 = (const float*)d_in[4];
    const float* Wl2 = (const float*)d_in[5];
    const float* bl2 = (const float*)d_in[6];
    const float* Wr2 = (const float*)d_in[7];
    const float* Wl3 = (const float*)d_in[8];
    const float* bl3 = (const float*)d_in[9];
    const float* Wr3 = (const float*)d_in[10];
    const float* Wout = (const float*)d_in[11];
    const float* bout = (const float*)d_in[12];
    float* out = (float*)d_out;

    const int N = in_sizes[0] / HD;       // 50000
    const int E = in_sizes[1] / 2;        // 800000
    const int NB = (N + BNODES - 1) >> BSH;   // 782 buckets

    // Workspace layout — float4-accessed buffers first (16B alignment).
    float* hMean  = (float*)d_ws;                    // [N*64] f32
    float* hA     = hMean + (size_t)N * HD;          // [N*64] f32
    float* hB     = hA + (size_t)N * HD;             // [N*64] f32
    _Float16* hHalf = (_Float16*)(hB + (size_t)N * HD);  // [N*64] f16 shadow
    int* ebuf     = (int*)(hHalf + (size_t)N * HD);  // [E] packed src<<6|dstLow
    int* colidx   = ebuf + E;                        // [E] CSR
    int* rowptr   = colidx + E;                      // [N+1]
    float* invdeg = (float*)(rowptr + N + 1);        // [N]
    int* bsize    = (int*)(invdeg + N);              // [784]
    int* bbase    = bsize + 784;                     // [785]
    int* bcur     = bbase + 785;                     // [784]

    hipMemsetAsync(bsize, 0, 784 * sizeof(int), stream);

    hist_kernel<<<128, 256, 0, stream>>>(ei, bsize, E, NB);
    bscan_kernel<<<1, 256, 0, stream>>>(bsize, bbase, bcur, NB, E);
    part_kernel<<<(E + CHUNK - 1) / CHUNK, 256, 0, stream>>>(ei, bcur, ebuf, E, NB);
    bsort_kernel<<<NB, 256, 0, stream>>>(ebuf, bbase, colidx, rowptr, invdeg, N, E);

    const int n64 = N * HD;
    tohalf_kernel<<<(n64 / 8 + 255) / 256, 256, 0, stream>>>(x, hHalf, n64);

    const int agrid = 2048;               // 8192 waves, grid-stride over tiles
    const int ggrid = (N + 63) / 64;      // 782 tiles

    aggregate_kernel<<<agrid, 256, 0, stream>>>(hHalf, hMean, rowptr, colidx, invdeg, N);
    sage_gemm<<<ggrid, 256, 0, stream>>>(hMean, x, hA, hHalf, Wl1, bl1, Wr1, N);

    aggregate_kernel<<<agrid, 256, 0, stream>>>(hHalf, hMean, rowptr, colidx, invdeg, N);
    sage_gemm<<<ggrid, 256, 0, stream>>>(hMean, hA, hB, hHalf, Wl2, bl2, Wr2, N);

    aggregate_kernel<<<agrid, 256, 0, stream>>>(hHalf, hMean, rowptr, colidx, invdeg, N);
    sage_gemm_out<<<ggrid, 256, 0, stream>>>(hMean, hB, Wl3, bl3, Wr3, Wout, bout, out, N);
}

// Round 11
// 242.078 us; speedup vs baseline: 5.0442x; 1.0021x over previous
//
#include <hip/hip_runtime.h>

#define HD 64
#define SLOPE 0.01f
#define BSH 6                    // 64 nodes per bucket
#define BNODES 64
#define CHUNK 4096               // edges per partition block (LDS 38KB -> 4 blk/CU)

// ---------------------------------------------------------------------------
// Build v3 (R8-proven): bucket histogram -> scan -> localized partition ->
// per-bucket counting sort. ~8 MB write traffic vs naive fill's 53 MB.
// ---------------------------------------------------------------------------

__global__ __launch_bounds__(256) void hist_kernel(const int* __restrict__ ei,
                                                   int* __restrict__ bsize,
                                                   int E, int nb) {
    __shared__ int h[784];
    const int t = threadIdx.x;
    for (int i = t; i < nb; i += 256) h[i] = 0;
    __syncthreads();
    const int stride = gridDim.x * 256;
    for (int e = blockIdx.x * 256 + t; e < E; e += stride)
        atomicAdd(&h[ei[E + e] >> BSH], 1);
    __syncthreads();
    for (int i = t; i < nb; i += 256) {
        int v = h[i];
        if (v) atomicAdd(&bsize[i], v);
    }
}

__global__ __launch_bounds__(256) void bscan_kernel(const int* __restrict__ bsize,
                                                    int* __restrict__ bbase,
                                                    int* __restrict__ bcur,
                                                    int nb, int E) {
    __shared__ int wsum[4];
    const int t = threadIdx.x, lane = t & 63, wid = t >> 6;
    int v[4];
    int s = 0;
    #pragma unroll
    for (int j = 0; j < 4; ++j) {
        int i = t * 4 + j;
        v[j] = (i < nb) ? bsize[i] : 0;
        s += v[j];
    }
    int x = s;
    #pragma unroll
    for (int d = 1; d < 64; d <<= 1) { int y = __shfl_up(x, d, 64); if (lane >= d) x += y; }
    if (lane == 63) wsum[wid] = x;
    __syncthreads();
    if (wid == 0 && lane < 4) {
        int ws = wsum[lane], xs = ws;
        #pragma unroll
        for (int d = 1; d < 4; d <<= 1) { int y = __shfl_up(xs, d, 64); if (lane >= d) xs += y; }
        wsum[lane] = xs - ws;
    }
    __syncthreads();
    int base = wsum[wid] + (x - s);
    #pragma unroll
    for (int j = 0; j < 4; ++j) {
        int i = t * 4 + j;
        if (i < nb) { bbase[i] = base; bcur[i] = base; }
        base += v[j];
    }
    if (t == 0) bbase[nb] = E;
}

__global__ __launch_bounds__(256) void part_kernel(const int* __restrict__ ei,
                                                   int* __restrict__ bcur,
                                                   int* __restrict__ ebuf,
                                                   int E, int nb) {
    __shared__ int pk_s[CHUNK];
    __shared__ int mt_s[CHUNK];
    __shared__ int hist[784];
    __shared__ int sbase[784];
    const int t = threadIdx.x;
    const int c0 = blockIdx.x * CHUNK;
    const int cnt = min(CHUNK, E - c0);
    for (int i = t; i < nb; i += 256) hist[i] = 0;
    __syncthreads();
    for (int i = t; i < cnt; i += 256) {
        int src = ei[c0 + i];
        int dst = ei[E + c0 + i];
        int b = dst >> BSH;
        pk_s[i] = (src << BSH) | (dst & (BNODES - 1));
        int r = atomicAdd(&hist[b], 1);
        mt_s[i] = (b << 12) | r;           // rank < CHUNK = 2^12
    }
    __syncthreads();
    for (int b = t; b < nb; b += 256) {
        int h = hist[b];
        if (h) sbase[b] = atomicAdd(&bcur[b], h);
    }
    __syncthreads();
    for (int i = t; i < cnt; i += 256) {
        int m = mt_s[i];
        int b = m >> 12;
        ebuf[sbase[b] + (m & (CHUNK - 1))] = pk_s[i];
    }
}

__global__ __launch_bounds__(256) void bsort_kernel(const int* __restrict__ ebuf,
                                                    const int* __restrict__ bbase,
                                                    int* __restrict__ colidx,
                                                    int* __restrict__ rowptr,
                                                    float* __restrict__ invdeg,
                                                    int n, int E) {
    __shared__ int cnt[BNODES];
    const int b = blockIdx.x;
    const int t = threadIdx.x;
    const int ebeg = bbase[b], eend = bbase[b + 1];
    if (t < BNODES) cnt[t] = 0;
    __syncthreads();
    for (int k = ebeg + t; k < eend; k += 256)
        atomicAdd(&cnt[ebuf[k] & (BNODES - 1)], 1);
    __syncthreads();
    if (t < BNODES) {                      // wave 0: scan the 64 counters
        int v = cnt[t];
        int x = v;
        #pragma unroll
        for (int d = 1; d < 64; d <<= 1) { int y = __shfl_up(x, d, 64); if (t >= d) x += y; }
        int excl = x - v;
        int node = b * BNODES + t;
        if (node < n) {
            rowptr[node] = ebeg + excl;
            invdeg[node] = 1.0f / (float)((v > 1) ? v : 1);
        }
        cnt[t] = excl;                     // becomes the running cursor
    }
    if (b == 0 && t == 0) rowptr[n] = E;
    __syncthreads();
    for (int k = ebeg + t; k < eend; k += 256) {
        int p = ebuf[k];
        int r = atomicAdd(&cnt[p & (BNODES - 1)], 1);
        colidx[ebeg + r] = p >> BSH;
    }
}

// ---------------------------------------------------------------------------
// fp32 -> fp16 shadow copy (round-to-nearest). Grid-stride, 8 elems/thread.
// ---------------------------------------------------------------------------

__global__ __launch_bounds__(256) void tohalf_kernel(const float* __restrict__ in,
                                                     _Float16* __restrict__ out,
                                                     int n64) {
    int i = (blockIdx.x * 256 + threadIdx.x) * 8;
    if (i >= n64) return;
    float4 a = *(const float4*)(in + i);
    float4 b = *(const float4*)(in + i + 4);
    _Float16 o[8] = {(_Float16)a.x, (_Float16)a.y, (_Float16)a.z, (_Float16)a.w,
                     (_Float16)b.x, (_Float16)b.y, (_Float16)b.z, (_Float16)b.w};
    *(float4*)(out + i) = *(float4*)o;     // 16B store of 8 halves
}

// ---------------------------------------------------------------------------
// Aggregation v6: 8 nodes per wave, 8-lane group per node (fp16 row = 128B =
// 8 lanes x 16B). One load instruction now fetches 8 rows (vs 4 in v5) and
// the 8-deep batch keeps 64 rows in flight per wave (vs 32), with half the
// VMEM instruction count. Unconditional clamp-to-row-0 loads + select
// multiplier (R10-proven); all __shfl executed by ALL lanes (R3 lesson).
// ---------------------------------------------------------------------------

__global__ __launch_bounds__(256) void aggregate_kernel(
    const _Float16* __restrict__ h16, float* __restrict__ mean_out,
    const int* __restrict__ rowptr, const int* __restrict__ colidx,
    const float* __restrict__ inv_deg, int n) {
    const int lane = threadIdx.x & 63;
    const int wslot = threadIdx.x >> 6;
    const int g = lane >> 3;     // node slot within tile (0..7)
    const int c8 = lane & 7;     // 16B chunk (8 halves) of the 128B row
    const float4* __restrict__ h4 = (const float4*)h16;   // row = 8 float4
    float4* __restrict__ m4 = (float4*)mean_out;

    const int ntiles = gridDim.x * 4;
    const int ntile_tot = (n + 7) >> 3;

    for (int tile = blockIdx.x * 4 + wslot; tile < ntile_tot; tile += ntiles) {
        const int node = tile * 8 + g;
        const bool valid = node < n;
        int beg = 0, end = 0; float idg = 0.f;
        if (valid) {
            beg = rowptr[node];
            end = rowptr[node + 1];
            idg = inv_deg[node];
        }
        const int deg = end - beg;

        int md = deg;                              // wave-uniform max degree
        md = max(md, __shfl_xor(md, 8, 64));
        md = max(md, __shfl_xor(md, 16, 64));
        md = max(md, __shfl_xor(md, 32, 64));

        float4 accA = {0.f, 0.f, 0.f, 0.f};
        float4 accB = {0.f, 0.f, 0.f, 0.f};
        for (int t0 = 0; t0 < md; t0 += 8) {
            const int off = beg + t0 + c8;
            int ci = (off < end) ? colidx[off] : 0;

            int idx[8];
            #pragma unroll
            for (int k = 0; k < 8; ++k)            // 8 independent bpermutes
                idx[k] = __shfl(ci, g * 8 + k, 64);
            float4 vv[8];
            float sel[8];
            #pragma unroll
            for (int k = 0; k < 8; ++k) {          // 8 unconditional loads
                const bool p = (t0 + k) < deg;     // group-uniform
                const int safe = p ? idx[k] : 0;   // row 0 = L1-hot
                sel[k] = p ? 1.0f : 0.0f;
                vv[k] = h4[(size_t)safe * 8 + c8]; // 16B = 8 halves
            }
            #pragma unroll
            for (int k = 0; k < 8; ++k) {
                const _Float16* hp = (const _Float16*)&vv[k];
                accA.x += sel[k] * (float)hp[0];
                accA.y += sel[k] * (float)hp[1];
                accA.z += sel[k] * (float)hp[2];
                accA.w += sel[k] * (float)hp[3];
                accB.x += sel[k] * (float)hp[4];
                accB.y += sel[k] * (float)hp[5];
                accB.z += sel[k] * (float)hp[6];
                accB.w += sel[k] * (float)hp[7];
            }
        }
        if (valid) {
            float4 oA = {accA.x * idg, accA.y * idg, accA.z * idg, accA.w * idg};
            float4 oB = {accB.x * idg, accB.y * idg, accB.z * idg, accB.w * idg};
            m4[(size_t)node * 16 + c8 * 2 + 0] = oA;   // group writes 256B row
            m4[(size_t)node * 16 + c8 * 2 + 1] = oB;
        }
    }
}

// ---------------------------------------------------------------------------
// Dense: out = leaky(mean @ Wl + bl + self @ Wr), 64x64 tile per block,
// 4x4 register blocking per thread — constant-indexed frags, no spill.
// sage_gemm additionally stores the fp16 shadow for the next layer's gather.
// ---------------------------------------------------------------------------

#define FMA4(acc, am, b0, b1, b2, b3)                                  \
    acc.x += am.x * b0.x + am.y * b1.x + am.z * b2.x + am.w * b3.x;    \
    acc.y += am.x * b0.y + am.y * b1.y + am.z * b2.y + am.w * b3.y;    \
    acc.z += am.x * b0.z + am.y * b1.z + am.z * b2.z + am.w * b3.z;    \
    acc.w += am.x * b0.w + am.y * b1.w + am.z * b2.w + am.w * b3.w;

#define GEMM_BODY(EXTRA_SHARED)                                             \
    __shared__ float sA[64 * 68];                                           \
    __shared__ float sS[64 * 68];                                           \
    __shared__ float sWl[64 * 64];                                          \
    __shared__ float sWr[64 * 64];                                          \
    EXTRA_SHARED                                                            \
    const int t = threadIdx.x;                                              \
    const int r0 = t & 15;                                                  \
    const int j0 = (t >> 4) * 4;                                            \
    const int base = blockIdx.x * 64;                                       \
    const int rows = min(64, n - base);                                     \
    const float4* __restrict__ m4 = (const float4*)mean;                    \
    const float4* __restrict__ h4 = (const float4*)h_in;                    \
    _Pragma("unroll")                                                       \
    for (int idx = 0; idx < 4; ++idx) {                                     \
        int i = t + idx * 256;                                              \
        ((float4*)sWl)[i] = ((const float4*)Wl)[i];                         \
        ((float4*)sWr)[i] = ((const float4*)Wr)[i];                         \
    }                                                                       \
    _Pragma("unroll")                                                       \
    for (int idx = 0; idx < 4; ++idx) {                                     \
        int i = t + idx * 256;                                              \
        int r = i >> 4, c4 = i & 15;                                        \
        float4 va = {0.f, 0.f, 0.f, 0.f}, vs = {0.f, 0.f, 0.f, 0.f};        \
        if (r < rows) {                                                     \
            va = m4[(size_t)(base + r) * 16 + c4];                          \
            vs = h4[(size_t)(base + r) * 16 + c4];                          \
        }                                                                   \
        *(float4*)(sA + r * 68 + 4 * c4) = va;                              \
        *(float4*)(sS + r * 68 + 4 * c4) = vs;                              \
    }                                                                       \
    __syncthreads();                                                        \
    const float4 bias = *(const float4*)(bl + j0);                          \
    float4 acc0 = bias, acc1 = bias, acc2 = bias, acc3 = bias;              \
    _Pragma("unroll 2")                                                     \
    for (int k4 = 0; k4 < 16; ++k4) {                                       \
        float4 b0 = *(const float4*)(sWl + (4 * k4 + 0) * 64 + j0);         \
        float4 b1 = *(const float4*)(sWl + (4 * k4 + 1) * 64 + j0);         \
        float4 b2 = *(const float4*)(sWl + (4 * k4 + 2) * 64 + j0);         \
        float4 b3 = *(const float4*)(sWl + (4 * k4 + 3) * 64 + j0);         \
        float4 a0 = *(const float4*)(sA + (r0 +  0) * 68 + 4 * k4);         \
        float4 a1 = *(const float4*)(sA + (r0 + 16) * 68 + 4 * k4);         \
        float4 a2 = *(const float4*)(sA + (r0 + 32) * 68 + 4 * k4);         \
        float4 a3 = *(const float4*)(sA + (r0 + 48) * 68 + 4 * k4);         \
        FMA4(acc0, a0, b0, b1, b2, b3)                                      \
        FMA4(acc1, a1, b0, b1, b2, b3)                                      \
        FMA4(acc2, a2, b0, b1, b2, b3)                                      \
        FMA4(acc3, a3, b0, b1, b2, b3)                                      \
        b0 = *(const float4*)(sWr + (4 * k4 + 0) * 64 + j0);                \
        b1 = *(const float4*)(sWr + (4 * k4 + 1) * 64 + j0);                \
        b2 = *(const float4*)(sWr + (4 * k4 + 2) * 64 + j0);                \
        b3 = *(const float4*)(sWr + (4 * k4 + 3) * 64 + j0);                \
        a0 = *(const float4*)(sS + (r0 +  0) * 68 + 4 * k4);                \
        a1 = *(const float4*)(sS + (r0 + 16) * 68 + 4 * k4);                \
        a2 = *(const float4*)(sS + (r0 + 32) * 68 + 4 * k4);                \
        a3 = *(const float4*)(sS + (r0 + 48) * 68 + 4 * k4);                \
        FMA4(acc0, a0, b0, b1, b2, b3)                                      \
        FMA4(acc1, a1, b0, b1, b2, b3)                                      \
        FMA4(acc2, a2, b0, b1, b2, b3)                                      \
        FMA4(acc3, a3, b0, b1, b2, b3)                                      \
    }                                                                       \
    acc0.x = (acc0.x > 0.f) ? acc0.x : SLOPE * acc0.x;                      \
    acc0.y = (acc0.y > 0.f) ? acc0.y : SLOPE * acc0.y;                      \
    acc0.z = (acc0.z > 0.f) ? acc0.z : SLOPE * acc0.z;                      \
    acc0.w = (acc0.w > 0.f) ? acc0.w : SLOPE * acc0.w;                      \
    acc1.x = (acc1.x > 0.f) ? acc1.x : SLOPE * acc1.x;                      \
    acc1.y = (acc1.y > 0.f) ? acc1.y : SLOPE * acc1.y;                      \
    acc1.z = (acc1.z > 0.f) ? acc1.z : SLOPE * acc1.z;                      \
    acc1.w = (acc1.w > 0.f) ? acc1.w : SLOPE * acc1.w;                      \
    acc2.x = (acc2.x > 0.f) ? acc2.x : SLOPE * acc2.x;                      \
    acc2.y = (acc2.y > 0.f) ? acc2.y : SLOPE * acc2.y;                      \
    acc2.z = (acc2.z > 0.f) ? acc2.z : SLOPE * acc2.z;                      \
    acc2.w = (acc2.w > 0.f) ? acc2.w : SLOPE * acc2.w;                      \
    acc3.x = (acc3.x > 0.f) ? acc3.x : SLOPE * acc3.x;                      \
    acc3.y = (acc3.y > 0.f) ? acc3.y : SLOPE * acc3.y;                      \
    acc3.z = (acc3.z > 0.f) ? acc3.z : SLOPE * acc3.z;                      \
    acc3.w = (acc3.w > 0.f) ? acc3.w : SLOPE * acc3.w;

__global__ __launch_bounds__(256, 2) void sage_gemm(
    const float* __restrict__ mean, const float* __restrict__ h_in,
    float* __restrict__ h_out, _Float16* __restrict__ h16_out,
    const float* __restrict__ Wl, const float* __restrict__ bl,
    const float* __restrict__ Wr, int n) {
    GEMM_BODY()
    #define STORE_ROW(S, ACC)                                               \
        { int r = r0 + 16 * S;                                              \
          if (r < rows) {                                                   \
              *(float4*)(h_out + (size_t)(base + r) * HD + j0) = ACC;       \
              _Float16 o[4] = {(_Float16)ACC.x, (_Float16)ACC.y,            \
                               (_Float16)ACC.z, (_Float16)ACC.w};           \
              *(float2*)(h16_out + (size_t)(base + r) * HD + j0)            \
                  = *(float2*)o;                                            \
          } }
    STORE_ROW(0, acc0)
    STORE_ROW(1, acc1)
    STORE_ROW(2, acc2)
    STORE_ROW(3, acc3)
    #undef STORE_ROW
}

__global__ __launch_bounds__(256, 2) void sage_gemm_out(
    const float* __restrict__ mean, const float* __restrict__ h_in,
    const float* __restrict__ Wl, const float* __restrict__ bl,
    const float* __restrict__ Wr,
    const float* __restrict__ Wout, const float* __restrict__ bout,
    float* __restrict__ out, int n) {
    GEMM_BODY(__shared__ float s_part[16][64];)
    const float4 w4 = *(const float4*)(Wout + j0);
    const int jg = t >> 4;
    s_part[jg][r0 +  0] = acc0.x * w4.x + acc0.y * w4.y + acc0.z * w4.z + acc0.w * w4.w;
    s_part[jg][r0 + 16] = acc1.x * w4.x + acc1.y * w4.y + acc1.z * w4.z + acc1.w * w4.w;
    s_part[jg][r0 + 32] = acc2.x * w4.x + acc2.y * w4.y + acc2.z * w4.z + acc2.w * w4.w;
    s_part[jg][r0 + 48] = acc3.x * w4.x + acc3.y * w4.y + acc3.z * w4.z + acc3.w * w4.w;
    __syncthreads();
    if (t < 64) {
        float sum = 0.f;
        #pragma unroll
        for (int g = 0; g < 16; ++g) sum += s_part[g][t];
        if (t < rows) out[base + t] = sum + bout[0];
    }
}

// ---------------------------------------------------------------------------

extern "C" void kernel_launch(void* const* d_in, const int* in_sizes, int n_in,
                              void* d_out, int out_size, void* d_ws, size_t ws_size,
                              hipStream_t stream) {
    const float* x   = (const float*)d_in[0];
    const int* ei    = (const int*)d_in[1];
    const float* Wl1 = (const float*)d_in[2];
    const float* bl1 = (const float*)d_in[3];
    const float* Wr1 = (const float*)d_in[4];
    const float* Wl2 = (const float*)d_in[5];
    const float* bl2 = (const float*)d_in[6];
    const float* Wr2 = (const float*)d_in[7];
    const float* Wl3 = (const float*)d_in[8];
    const float* bl3 = (const float*)d_in[9];
    const float* Wr3 = (const float*)d_in[10];
    const float* Wout = (const float*)d_in[11];
    const float* bout = (const float*)d_in[12];
    float* out = (float*)d_out;

    const int N = in_sizes[0] / HD;       // 50000
    const int E = in_sizes[1] / 2;        // 800000
    const int NB = (N + BNODES - 1) >> BSH;   // 782 buckets

    // Workspace layout — float4-accessed buffers first (16B alignment).
    float* hMean  = (float*)d_ws;                    // [N*64] f32
    float* hA     = hMean + (size_t)N * HD;          // [N*64] f32
    float* hB     = hA + (size_t)N * HD;             // [N*64] f32
    _Float16* hHalf = (_Float16*)(hB + (size_t)N * HD);  // [N*64] f16 shadow
    int* ebuf     = (int*)(hHalf + (size_t)N * HD);  // [E] packed src<<6|dstLow
    int* colidx   = ebuf + E;                        // [E] CSR
    int* rowptr   = colidx + E;                      // [N+1]
    float* invdeg = (float*)(rowptr + N + 1);        // [N]
    int* bsize    = (int*)(invdeg + N);              // [784]
    int* bbase    = bsize + 784;                     // [785]
    int* bcur     = bbase + 785;                     // [784]

    hipMemsetAsync(bsize, 0, 784 * sizeof(int), stream);

    hist_kernel<<<128, 256, 0, stream>>>(ei, bsize, E, NB);
    bscan_kernel<<<1, 256, 0, stream>>>(bsize, bbase, bcur, NB, E);
    part_kernel<<<(E + CHUNK - 1) / CHUNK, 256, 0, stream>>>(ei, bcur, ebuf, E, NB);
    bsort_kernel<<<NB, 256, 0, stream>>>(ebuf, bbase, colidx, rowptr, invdeg, N, E);

    const int n64 = N * HD;
    tohalf_kernel<<<(n64 / 8 + 255) / 256, 256, 0, stream>>>(x, hHalf, n64);

    const int agrid = 1568;               // 6272 waves ~= 6250 tiles (1/wave)
    const int ggrid = (N + 63) / 64;      // 782 tiles

    aggregate_kernel<<<agrid, 256, 0, stream>>>(hHalf, hMean, rowptr, colidx, invdeg, N);
    sage_gemm<<<ggrid, 256, 0, stream>>>(hMean, x, hA, hHalf, Wl1, bl1, Wr1, N);

    aggregate_kernel<<<agrid, 256, 0, stream>>>(hHalf, hMean, rowptr, colidx, invdeg, N);
    sage_gemm<<<ggrid, 256, 0, stream>>>(hMean, hA, hB, hHalf, Wl2, bl2, Wr2, N);

    aggregate_kernel<<<agrid, 256, 0, stream>>>(hHalf, hMean, rowptr, colidx, invdeg, N);
    sage_gemm_out<<<ggrid, 256, 0, stream>>>(hMean, hB, Wl3, bl3, Wr3, Wout, bout, out, N);
}

// Round 12
// 240.716 us; speedup vs baseline: 5.0727x; 1.0057x over previous
//
#include <hip/hip_runtime.h>

#define HD 64
#define SLOPE 0.01f
#define BSH 6                    // 64 nodes per bucket
#define BNODES 64
#define CHUNK 4096               // edges per partition block (LDS 38KB -> 4 blk/CU)

// ---------------------------------------------------------------------------
// Build v3 (R8-proven): bucket histogram -> scan -> localized partition ->
// per-bucket counting sort. ~8 MB write traffic vs naive fill's 53 MB.
// ---------------------------------------------------------------------------

__global__ __launch_bounds__(256) void hist_kernel(const int* __restrict__ ei,
                                                   int* __restrict__ bsize,
                                                   int E, int nb) {
    __shared__ int h[784];
    const int t = threadIdx.x;
    for (int i = t; i < nb; i += 256) h[i] = 0;
    __syncthreads();
    const int stride = gridDim.x * 256;
    for (int e = blockIdx.x * 256 + t; e < E; e += stride)
        atomicAdd(&h[ei[E + e] >> BSH], 1);
    __syncthreads();
    for (int i = t; i < nb; i += 256) {
        int v = h[i];
        if (v) atomicAdd(&bsize[i], v);
    }
}

__global__ __launch_bounds__(256) void bscan_kernel(const int* __restrict__ bsize,
                                                    int* __restrict__ bbase,
                                                    int* __restrict__ bcur,
                                                    int nb, int E) {
    __shared__ int wsum[4];
    const int t = threadIdx.x, lane = t & 63, wid = t >> 6;
    int v[4];
    int s = 0;
    #pragma unroll
    for (int j = 0; j < 4; ++j) {
        int i = t * 4 + j;
        v[j] = (i < nb) ? bsize[i] : 0;
        s += v[j];
    }
    int x = s;
    #pragma unroll
    for (int d = 1; d < 64; d <<= 1) { int y = __shfl_up(x, d, 64); if (lane >= d) x += y; }
    if (lane == 63) wsum[wid] = x;
    __syncthreads();
    if (wid == 0 && lane < 4) {
        int ws = wsum[lane], xs = ws;
        #pragma unroll
        for (int d = 1; d < 4; d <<= 1) { int y = __shfl_up(xs, d, 64); if (lane >= d) xs += y; }
        wsum[lane] = xs - ws;
    }
    __syncthreads();
    int base = wsum[wid] + (x - s);
    #pragma unroll
    for (int j = 0; j < 4; ++j) {
        int i = t * 4 + j;
        if (i < nb) { bbase[i] = base; bcur[i] = base; }
        base += v[j];
    }
    if (t == 0) bbase[nb] = E;
}

__global__ __launch_bounds__(256) void part_kernel(const int* __restrict__ ei,
                                                   int* __restrict__ bcur,
                                                   int* __restrict__ ebuf,
                                                   int E, int nb) {
    __shared__ int pk_s[CHUNK];
    __shared__ int mt_s[CHUNK];
    __shared__ int hist[784];
    __shared__ int sbase[784];
    const int t = threadIdx.x;
    const int c0 = blockIdx.x * CHUNK;
    const int cnt = min(CHUNK, E - c0);
    for (int i = t; i < nb; i += 256) hist[i] = 0;
    __syncthreads();
    for (int i = t; i < cnt; i += 256) {
        int src = ei[c0 + i];
        int dst = ei[E + c0 + i];
        int b = dst >> BSH;
        pk_s[i] = (src << BSH) | (dst & (BNODES - 1));
        int r = atomicAdd(&hist[b], 1);
        mt_s[i] = (b << 12) | r;           // rank < CHUNK = 2^12
    }
    __syncthreads();
    for (int b = t; b < nb; b += 256) {
        int h = hist[b];
        if (h) sbase[b] = atomicAdd(&bcur[b], h);
    }
    __syncthreads();
    for (int i = t; i < cnt; i += 256) {
        int m = mt_s[i];
        int b = m >> 12;
        ebuf[sbase[b] + (m & (CHUNK - 1))] = pk_s[i];
    }
}

__global__ __launch_bounds__(256) void bsort_kernel(const int* __restrict__ ebuf,
                                                    const int* __restrict__ bbase,
                                                    int* __restrict__ colidx,
                                                    int* __restrict__ rowptr,
                                                    float* __restrict__ invdeg,
                                                    int n, int E) {
    __shared__ int cnt[BNODES];
    const int b = blockIdx.x;
    const int t = threadIdx.x;
    const int ebeg = bbase[b], eend = bbase[b + 1];
    if (t < BNODES) cnt[t] = 0;
    __syncthreads();
    for (int k = ebeg + t; k < eend; k += 256)
        atomicAdd(&cnt[ebuf[k] & (BNODES - 1)], 1);
    __syncthreads();
    if (t < BNODES) {                      // wave 0: scan the 64 counters
        int v = cnt[t];
        int x = v;
        #pragma unroll
        for (int d = 1; d < 64; d <<= 1) { int y = __shfl_up(x, d, 64); if (t >= d) x += y; }
        int excl = x - v;
        int node = b * BNODES + t;
        if (node < n) {
            rowptr[node] = ebeg + excl;
            invdeg[node] = 1.0f / (float)((v > 1) ? v : 1);
        }
        cnt[t] = excl;                     // becomes the running cursor
    }
    if (b == 0 && t == 0) rowptr[n] = E;
    __syncthreads();
    for (int k = ebeg + t; k < eend; k += 256) {
        int p = ebuf[k];
        int r = atomicAdd(&cnt[p & (BNODES - 1)], 1);
        colidx[ebeg + r] = p >> BSH;
    }
}

// ---------------------------------------------------------------------------
// fp32 -> fp16 shadow copy (round-to-nearest). Grid-stride, 8 elems/thread.
// ---------------------------------------------------------------------------

__global__ __launch_bounds__(256) void tohalf_kernel(const float* __restrict__ in,
                                                     _Float16* __restrict__ out,
                                                     int n64) {
    int i = (blockIdx.x * 256 + threadIdx.x) * 8;
    if (i >= n64) return;
    float4 a = *(const float4*)(in + i);
    float4 b = *(const float4*)(in + i + 4);
    _Float16 o[8] = {(_Float16)a.x, (_Float16)a.y, (_Float16)a.z, (_Float16)a.w,
                     (_Float16)b.x, (_Float16)b.y, (_Float16)b.z, (_Float16)b.w};
    *(float4*)(out + i) = *(float4*)o;     // 16B store of 8 halves
}

// ---------------------------------------------------------------------------
// Fused SAGE layer: block = one 64-node tile. Phase A aggregates the tile's
// mean directly into LDS (v6 gather: 8 nodes/wave-pass, 8-lane groups,
// unconditional clamp-to-row-0 loads + select multiplier; all __shfl by ALL
// lanes — R3 lesson). Phase B = R8-proven register-blocked GEMM from LDS.
// Deletes the hMean global round-trip and the per-layer agg->gemm drain.
// ---------------------------------------------------------------------------

#define FMA4(acc, am, b0, b1, b2, b3)                                  \
    acc.x += am.x * b0.x + am.y * b1.x + am.z * b2.x + am.w * b3.x;    \
    acc.y += am.x * b0.y + am.y * b1.y + am.z * b2.y + am.w * b3.y;    \
    acc.z += am.x * b0.z + am.y * b1.z + am.z * b2.z + am.w * b3.z;    \
    acc.w += am.x * b0.w + am.y * b1.w + am.z * b2.w + am.w * b3.w;

#define FUSED_BODY(EXTRA_SHARED)                                            \
    __shared__ float sA[64 * 68];     /* mean tile, f32, stride 68 */       \
    __shared__ float sS[64 * 68];     /* self tile */                       \
    __shared__ float sWl[64 * 64];                                          \
    __shared__ float sWr[64 * 64];                                          \
    EXTRA_SHARED                                                            \
    const int t = threadIdx.x;                                              \
    const int lane = t & 63;                                                \
    const int w = t >> 6;                                                   \
    const int base = blockIdx.x * 64;                                       \
    const int rows = min(64, n - base);                                     \
    const float4* __restrict__ hh4 = (const float4*)h_in;                   \
    /* stage W + self tile (streaming; completes long before gather) */     \
    _Pragma("unroll")                                                       \
    for (int idx = 0; idx < 4; ++idx) {                                     \
        int i = t + idx * 256;                                              \
        ((float4*)sWl)[i] = ((const float4*)Wl)[i];                         \
        ((float4*)sWr)[i] = ((const float4*)Wr)[i];                         \
    }                                                                       \
    _Pragma("unroll")                                                       \
    for (int idx = 0; idx < 4; ++idx) {                                     \
        int i = t + idx * 256;                                              \
        int r = i >> 4, cc = i & 15;                                        \
        float4 vs = {0.f, 0.f, 0.f, 0.f};                                   \
        if (r < rows) vs = hh4[(size_t)(base + r) * 16 + cc];               \
        *(float4*)(sS + r * 68 + 4 * cc) = vs;                              \
    }                                                                       \
    /* ---- phase A: aggregate into sA ---- */                              \
    {                                                                       \
        const int g = lane >> 3;      /* node slot 0..7 */                  \
        const int c8 = lane & 7;      /* 16B chunk of 128B fp16 row */      \
        const float4* __restrict__ g4 = (const float4*)h16;                 \
        _Pragma("unroll")                                                   \
        for (int pass = 0; pass < 2; ++pass) {                              \
            const int r = w * 16 + pass * 8 + g;   /* local row 0..63 */    \
            const int node = base + r;                                      \
            const bool valid = node < n;                                    \
            int beg = 0, end = 0; float idg = 0.f;                          \
            if (valid) {                                                    \
                beg = rowptr[node];                                         \
                end = rowptr[node + 1];                                     \
                idg = invdeg[node];                                         \
            }                                                               \
            const int deg = end - beg;                                      \
            int md = deg;                       /* wave-uniform max */      \
            md = max(md, __shfl_xor(md, 8, 64));                            \
            md = max(md, __shfl_xor(md, 16, 64));                           \
            md = max(md, __shfl_xor(md, 32, 64));                           \
            float4 accA = {0.f, 0.f, 0.f, 0.f};                             \
            float4 accB = {0.f, 0.f, 0.f, 0.f};                             \
            for (int t0 = 0; t0 < md; t0 += 8) {                            \
                const int off = beg + t0 + c8;                              \
                int ci = (off < end) ? colidx[off] : 0;                     \
                int idx[8];                                                 \
                _Pragma("unroll")                                           \
                for (int k = 0; k < 8; ++k)                                 \
                    idx[k] = __shfl(ci, g * 8 + k, 64);                     \
                float4 vv[8];                                               \
                float sel[8];                                               \
                _Pragma("unroll")                                           \
                for (int k = 0; k < 8; ++k) {                               \
                    const bool p = (t0 + k) < deg;                          \
                    const int safe = p ? idx[k] : 0;                        \
                    sel[k] = p ? 1.0f : 0.0f;                               \
                    vv[k] = g4[(size_t)safe * 8 + c8];                      \
                }                                                           \
                _Pragma("unroll")                                           \
                for (int k = 0; k < 8; ++k) {                               \
                    const _Float16* hp = (const _Float16*)&vv[k];           \
                    accA.x += sel[k] * (float)hp[0];                        \
                    accA.y += sel[k] * (float)hp[1];                        \
                    accA.z += sel[k] * (float)hp[2];                        \
                    accA.w += sel[k] * (float)hp[3];                        \
                    accB.x += sel[k] * (float)hp[4];                        \
                    accB.y += sel[k] * (float)hp[5];                        \
                    accB.z += sel[k] * (float)hp[6];                        \
                    accB.w += sel[k] * (float)hp[7];                        \
                }                                                           \
            }                                                               \
            float4 oA = {accA.x * idg, accA.y * idg, accA.z * idg, accA.w * idg}; \
            float4 oB = {accB.x * idg, accB.y * idg, accB.z * idg, accB.w * idg}; \
            *(float4*)(sA + r * 68 + c8 * 8 + 0) = oA;                      \
            *(float4*)(sA + r * 68 + c8 * 8 + 4) = oB;                      \
        }                                                                   \
    }                                                                       \
    __syncthreads();                                                        \
    /* ---- phase B: register-blocked GEMM ---- */                          \
    const int r0 = t & 15;                                                  \
    const int j0 = (t >> 4) * 4;                                            \
    const float4 bias = *(const float4*)(bl + j0);                          \
    float4 acc0 = bias, acc1 = bias, acc2 = bias, acc3 = bias;              \
    _Pragma("unroll 2")                                                     \
    for (int k4 = 0; k4 < 16; ++k4) {                                       \
        float4 b0 = *(const float4*)(sWl + (4 * k4 + 0) * 64 + j0);         \
        float4 b1 = *(const float4*)(sWl + (4 * k4 + 1) * 64 + j0);         \
        float4 b2 = *(const float4*)(sWl + (4 * k4 + 2) * 64 + j0);         \
        float4 b3 = *(const float4*)(sWl + (4 * k4 + 3) * 64 + j0);         \
        float4 a0 = *(const float4*)(sA + (r0 +  0) * 68 + 4 * k4);         \
        float4 a1 = *(const float4*)(sA + (r0 + 16) * 68 + 4 * k4);         \
        float4 a2 = *(const float4*)(sA + (r0 + 32) * 68 + 4 * k4);         \
        float4 a3 = *(const float4*)(sA + (r0 + 48) * 68 + 4 * k4);         \
        FMA4(acc0, a0, b0, b1, b2, b3)                                      \
        FMA4(acc1, a1, b0, b1, b2, b3)                                      \
        FMA4(acc2, a2, b0, b1, b2, b3)                                      \
        FMA4(acc3, a3, b0, b1, b2, b3)                                      \
        b0 = *(const float4*)(sWr + (4 * k4 + 0) * 64 + j0);                \
        b1 = *(const float4*)(sWr + (4 * k4 + 1) * 64 + j0);                \
        b2 = *(const float4*)(sWr + (4 * k4 + 2) * 64 + j0);                \
        b3 = *(const float4*)(sWr + (4 * k4 + 3) * 64 + j0);                \
        a0 = *(const float4*)(sS + (r0 +  0) * 68 + 4 * k4);                \
        a1 = *(const float4*)(sS + (r0 + 16) * 68 + 4 * k4);                \
        a2 = *(const float4*)(sS + (r0 + 32) * 68 + 4 * k4);                \
        a3 = *(const float4*)(sS + (r0 + 48) * 68 + 4 * k4);                \
        FMA4(acc0, a0, b0, b1, b2, b3)                                      \
        FMA4(acc1, a1, b0, b1, b2, b3)                                      \
        FMA4(acc2, a2, b0, b1, b2, b3)                                      \
        FMA4(acc3, a3, b0, b1, b2, b3)                                      \
    }                                                                       \
    acc0.x = (acc0.x > 0.f) ? acc0.x : SLOPE * acc0.x;                      \
    acc0.y = (acc0.y > 0.f) ? acc0.y : SLOPE * acc0.y;                      \
    acc0.z = (acc0.z > 0.f) ? acc0.z : SLOPE * acc0.z;                      \
    acc0.w = (acc0.w > 0.f) ? acc0.w : SLOPE * acc0.w;                      \
    acc1.x = (acc1.x > 0.f) ? acc1.x : SLOPE * acc1.x;                      \
    acc1.y = (acc1.y > 0.f) ? acc1.y : SLOPE * acc1.y;                      \
    acc1.z = (acc1.z > 0.f) ? acc1.z : SLOPE * acc1.z;                      \
    acc1.w = (acc1.w > 0.f) ? acc1.w : SLOPE * acc1.w;                      \
    acc2.x = (acc2.x > 0.f) ? acc2.x : SLOPE * acc2.x;                      \
    acc2.y = (acc2.y > 0.f) ? acc2.y : SLOPE * acc2.y;                      \
    acc2.z = (acc2.z > 0.f) ? acc2.z : SLOPE * acc2.z;                      \
    acc2.w = (acc2.w > 0.f) ? acc2.w : SLOPE * acc2.w;                      \
    acc3.x = (acc3.x > 0.f) ? acc3.x : SLOPE * acc3.x;                      \
    acc3.y = (acc3.y > 0.f) ? acc3.y : SLOPE * acc3.y;                      \
    acc3.z = (acc3.z > 0.f) ? acc3.z : SLOPE * acc3.z;                      \
    acc3.w = (acc3.w > 0.f) ? acc3.w : SLOPE * acc3.w;

__global__ __launch_bounds__(256, 2) void sage_fused(
    const _Float16* __restrict__ h16, const float* __restrict__ h_in,
    float* __restrict__ h_out, _Float16* __restrict__ h16_out,
    const int* __restrict__ rowptr, const int* __restrict__ colidx,
    const float* __restrict__ invdeg,
    const float* __restrict__ Wl, const float* __restrict__ bl,
    const float* __restrict__ Wr, int n) {
    FUSED_BODY()
    #define STORE_ROW(S, ACC)                                               \
        { int r = r0 + 16 * S;                                              \
          if (r < rows) {                                                   \
              *(float4*)(h_out + (size_t)(base + r) * HD + j0) = ACC;       \
              _Float16 o[4] = {(_Float16)ACC.x, (_Float16)ACC.y,            \
                               (_Float16)ACC.z, (_Float16)ACC.w};           \
              *(float2*)(h16_out + (size_t)(base + r) * HD + j0)            \
                  = *(float2*)o;                                            \
          } }
    STORE_ROW(0, acc0)
    STORE_ROW(1, acc1)
    STORE_ROW(2, acc2)
    STORE_ROW(3, acc3)
    #undef STORE_ROW
}

// Layer-3 variant: h3 never hits memory — dot with Wout, cross-wave LDS
// reduction, write out[node] directly.
__global__ __launch_bounds__(256, 2) void sage_fused_out(
    const _Float16* __restrict__ h16, const float* __restrict__ h_in,
    const int* __restrict__ rowptr, const int* __restrict__ colidx,
    const float* __restrict__ invdeg,
    const float* __restrict__ Wl, const float* __restrict__ bl,
    const float* __restrict__ Wr,
    const float* __restrict__ Wout, const float* __restrict__ bout,
    float* __restrict__ out, int n) {
    FUSED_BODY(__shared__ float s_part[16][64];)
    const float4 w4 = *(const float4*)(Wout + j0);
    const int jg = t >> 4;
    s_part[jg][r0 +  0] = acc0.x * w4.x + acc0.y * w4.y + acc0.z * w4.z + acc0.w * w4.w;
    s_part[jg][r0 + 16] = acc1.x * w4.x + acc1.y * w4.y + acc1.z * w4.z + acc1.w * w4.w;
    s_part[jg][r0 + 32] = acc2.x * w4.x + acc2.y * w4.y + acc2.z * w4.z + acc2.w * w4.w;
    s_part[jg][r0 + 48] = acc3.x * w4.x + acc3.y * w4.y + acc3.z * w4.z + acc3.w * w4.w;
    __syncthreads();
    if (t < 64) {
        float sum = 0.f;
        #pragma unroll
        for (int g2 = 0; g2 < 16; ++g2) sum += s_part[g2][t];
        if (t < rows) out[base + t] = sum + bout[0];
    }
}

// ---------------------------------------------------------------------------

extern "C" void kernel_launch(void* const* d_in, const int* in_sizes, int n_in,
                              void* d_out, int out_size, void* d_ws, size_t ws_size,
                              hipStream_t stream) {
    const float* x   = (const float*)d_in[0];
    const int* ei    = (const int*)d_in[1];
    const float* Wl1 = (const float*)d_in[2];
    const float* bl1 = (const float*)d_in[3];
    const float* Wr1 = (const float*)d_in[4];
    const float* Wl2 = (const float*)d_in[5];
    const float* bl2 = (const float*)d_in[6];
    const float* Wr2 = (const float*)d_in[7];
    const float* Wl3 = (const float*)d_in[8];
    const float* bl3 = (const float*)d_in[9];
    const float* Wr3 = (const float*)d_in[10];
    const float* Wout = (const float*)d_in[11];
    const float* bout = (const float*)d_in[12];
    float* out = (float*)d_out;

    const int N = in_sizes[0] / HD;       // 50000
    const int E = in_sizes[1] / 2;        // 800000
    const int NB = (N + BNODES - 1) >> BSH;   // 782 buckets

    // Workspace layout — float4-accessed buffers first (16B alignment).
    float* hA     = (float*)d_ws;                    // [N*64] f32
    float* hB     = hA + (size_t)N * HD;             // [N*64] f32
    _Float16* h16a = (_Float16*)(hB + (size_t)N * HD);   // [N*64] f16 gather src
    _Float16* h16b = h16a + (size_t)N * HD;          // [N*64] f16 gather dst
    int* ebuf     = (int*)(h16b + (size_t)N * HD);   // [E] packed src<<6|dstLow
    int* colidx   = ebuf + E;                        // [E] CSR
    int* rowptr   = colidx + E;                      // [N+1]
    float* invdeg = (float*)(rowptr + N + 1);        // [N]
    int* bsize    = (int*)(invdeg + N);              // [784]
    int* bbase    = bsize + 784;                     // [785]
    int* bcur     = bbase + 785;                     // [784]

    hipMemsetAsync(bsize, 0, 784 * sizeof(int), stream);

    hist_kernel<<<128, 256, 0, stream>>>(ei, bsize, E, NB);
    bscan_kernel<<<1, 256, 0, stream>>>(bsize, bbase, bcur, NB, E);
    part_kernel<<<(E + CHUNK - 1) / CHUNK, 256, 0, stream>>>(ei, bcur, ebuf, E, NB);
    bsort_kernel<<<NB, 256, 0, stream>>>(ebuf, bbase, colidx, rowptr, invdeg, N, E);

    const int n64 = N * HD;
    tohalf_kernel<<<(n64 / 8 + 255) / 256, 256, 0, stream>>>(x, h16a, n64);

    const int ggrid = (N + 63) / 64;      // 782 tiles

    sage_fused<<<ggrid, 256, 0, stream>>>(h16a, x, hA, h16b,
                                          rowptr, colidx, invdeg,
                                          Wl1, bl1, Wr1, N);
    sage_fused<<<ggrid, 256, 0, stream>>>(h16b, hA, hB, h16a,
                                          rowptr, colidx, invdeg,
                                          Wl2, bl2, Wr2, N);
    sage_fused_out<<<ggrid, 256, 0, stream>>>(h16a, hB,
                                              rowptr, colidx, invdeg,
                                              Wl3, bl3, Wr3, Wout, bout, out, N);
}

// Round 13
// 217.148 us; speedup vs baseline: 5.6233x; 1.1085x over previous
//
#include <hip/hip_runtime.h>

#define HD 64
#define SLOPE 0.01f
#define BSH 6                    // 64 nodes per bucket
#define BNODES 64
#define CHUNK 4096               // edges per partition block
#define SLOT 1536                // padded edge capacity per bucket (exp max ~1150)

// ---------------------------------------------------------------------------
// Build v4: padded-slot partition (no pre-count!) -> per-bucket counting
// sort emitting padded CSR (rowptr/rowend/invdeg). Deletes hist+bscan.
// ---------------------------------------------------------------------------

__global__ __launch_bounds__(256) void part_kernel(const int* __restrict__ ei,
                                                   int* __restrict__ bcur,
                                                   int* __restrict__ ebuf,
                                                   int E, int nb) {
    __shared__ int pk_s[CHUNK];
    __shared__ int mt_s[CHUNK];
    __shared__ int hist[784];
    __shared__ int sbase[784];
    const int t = threadIdx.x;
    const int c0 = blockIdx.x * CHUNK;
    const int cnt = min(CHUNK, E - c0);
    for (int i = t; i < nb; i += 256) hist[i] = 0;
    __syncthreads();
    for (int i = t; i < cnt; i += 256) {
        int src = ei[c0 + i];
        int dst = ei[E + c0 + i];
        int b = dst >> BSH;
        pk_s[i] = (src << BSH) | (dst & (BNODES - 1));
        int r = atomicAdd(&hist[b], 1);
        mt_s[i] = (b << 12) | r;           // rank < CHUNK = 2^12
    }
    __syncthreads();
    for (int b = t; b < nb; b += 256) {
        int h = hist[b];
        if (h) sbase[b] = b * SLOT + atomicAdd(&bcur[b], h);   // padded slot
    }
    __syncthreads();
    for (int i = t; i < cnt; i += 256) {
        int m = mt_s[i];
        int b = m >> 12;
        ebuf[sbase[b] + (m & (CHUNK - 1))] = pk_s[i];
    }
}

// One block per bucket: counting-sort by dst&63 -> padded CSR.
__global__ __launch_bounds__(256) void bsort_kernel(const int* __restrict__ ebuf,
                                                    const int* __restrict__ bcnt,
                                                    int* __restrict__ colidx,
                                                    int* __restrict__ rowptr,
                                                    int* __restrict__ rowend,
                                                    float* __restrict__ invdeg,
                                                    int n) {
    __shared__ int cnt[BNODES];
    const int b = blockIdx.x;
    const int t = threadIdx.x;
    const int ebeg = b * SLOT;
    const int eend = ebeg + bcnt[b];
    if (t < BNODES) cnt[t] = 0;
    __syncthreads();
    for (int k = ebeg + t; k < eend; k += 256)
        atomicAdd(&cnt[ebuf[k] & (BNODES - 1)], 1);
    __syncthreads();
    if (t < BNODES) {                      // wave 0: scan the 64 counters
        int v = cnt[t];
        int x = v;
        #pragma unroll
        for (int d = 1; d < 64; d <<= 1) { int y = __shfl_up(x, d, 64); if (t >= d) x += y; }
        int excl = x - v;
        int node = b * BNODES + t;
        if (node < n) {
            rowptr[node] = ebeg + excl;
            rowend[node] = ebeg + excl + v;
            invdeg[node] = 1.0f / (float)((v > 1) ? v : 1);
        }
        cnt[t] = excl;                     // becomes the running cursor
    }
    __syncthreads();
    for (int k = ebeg + t; k < eend; k += 256) {
        int p = ebuf[k];
        int r = atomicAdd(&cnt[p & (BNODES - 1)], 1);
        colidx[ebeg + r] = p >> BSH;
    }
}

// ---------------------------------------------------------------------------
// fp32 -> fp16 shadow copy (round-to-nearest). Grid-stride, 8 elems/thread.
// ---------------------------------------------------------------------------

__global__ __launch_bounds__(256) void tohalf_kernel(const float* __restrict__ in,
                                                     _Float16* __restrict__ out,
                                                     int n64) {
    int i = (blockIdx.x * 256 + threadIdx.x) * 8;
    if (i >= n64) return;
    float4 a = *(const float4*)(in + i);
    float4 b = *(const float4*)(in + i + 4);
    _Float16 o[8] = {(_Float16)a.x, (_Float16)a.y, (_Float16)a.z, (_Float16)a.w,
                     (_Float16)b.x, (_Float16)b.y, (_Float16)b.z, (_Float16)b.w};
    *(float4*)(out + i) = *(float4*)o;     // 16B store of 8 halves
}

// ---------------------------------------------------------------------------
// Fused SAGE layer v2: LDS diet — W read straight from global in phase B
// (per-instruction W addresses span one contiguous 256B -> 4 lines, L1-hot,
// broadcast in 16-lane groups). LDS = sA + sS = 34.8KB -> 4 blocks/CU
// (16 waves) so the gather phase regains latency hiding and real
// inter-block phase overlap exists. Phase A = v6 gather (R10/R11-proven).
// ---------------------------------------------------------------------------

#define FMA4(acc, am, b0, b1, b2, b3)                                  \
    acc.x += am.x * b0.x + am.y * b1.x + am.z * b2.x + am.w * b3.x;    \
    acc.y += am.x * b0.y + am.y * b1.y + am.z * b2.y + am.w * b3.y;    \
    acc.z += am.x * b0.z + am.y * b1.z + am.z * b2.z + am.w * b3.z;    \
    acc.w += am.x * b0.w + am.y * b1.w + am.z * b2.w + am.w * b3.w;

#define FUSED_BODY(EXTRA_SHARED)                                            \
    __shared__ float sA[64 * 68];     /* mean tile, f32, stride 68 */       \
    __shared__ float sS[64 * 68];     /* self tile */                       \
    EXTRA_SHARED                                                            \
    const int t = threadIdx.x;                                              \
    const int lane = t & 63;                                                \
    const int w = t >> 6;                                                   \
    const int base = blockIdx.x * 64;                                       \
    const int rows = min(64, n - base);                                     \
    const float4* __restrict__ hh4 = (const float4*)h_in;                   \
    /* stage self tile */                                                   \
    _Pragma("unroll")                                                       \
    for (int idx = 0; idx < 4; ++idx) {                                     \
        int i = t + idx * 256;                                              \
        int r = i >> 4, cc = i & 15;                                        \
        float4 vs = {0.f, 0.f, 0.f, 0.f};                                   \
        if (r < rows) vs = hh4[(size_t)(base + r) * 16 + cc];               \
        *(float4*)(sS + r * 68 + 4 * cc) = vs;                              \
    }                                                                       \
    /* ---- phase A: aggregate into sA ---- */                              \
    {                                                                       \
        const int g = lane >> 3;      /* node slot 0..7 */                  \
        const int c8 = lane & 7;      /* 16B chunk of 128B fp16 row */      \
        const float4* __restrict__ g4 = (const float4*)h16;                 \
        _Pragma("unroll")                                                   \
        for (int pass = 0; pass < 2; ++pass) {                              \
            const int r = w * 16 + pass * 8 + g;   /* local row 0..63 */    \
            const int node = base + r;                                      \
            const bool valid = node < n;                                    \
            int beg = 0, end = 0; float idg = 0.f;                          \
            if (valid) {                                                    \
                beg = rowptr[node];                                         \
                end = rowend[node];                                         \
                idg = invdeg[node];                                         \
            }                                                               \
            const int deg = end - beg;                                      \
            int md = deg;                       /* wave-uniform max */      \
            md = max(md, __shfl_xor(md, 8, 64));                            \
            md = max(md, __shfl_xor(md, 16, 64));                           \
            md = max(md, __shfl_xor(md, 32, 64));                           \
            float4 accA = {0.f, 0.f, 0.f, 0.f};                             \
            float4 accB = {0.f, 0.f, 0.f, 0.f};                             \
            for (int t0 = 0; t0 < md; t0 += 8) {                            \
                const int off = beg + t0 + c8;                              \
                int ci = (off < end) ? colidx[off] : 0;                     \
                int idx[8];                                                 \
                _Pragma("unroll")                                           \
                for (int k = 0; k < 8; ++k)                                 \
                    idx[k] = __shfl(ci, g * 8 + k, 64);                     \
                float4 vv[8];                                               \
                float sel[8];                                               \
                _Pragma("unroll")                                           \
                for (int k = 0; k < 8; ++k) {                               \
                    const bool p = (t0 + k) < deg;                          \
                    const int safe = p ? idx[k] : 0;                        \
                    sel[k] = p ? 1.0f : 0.0f;                               \
                    vv[k] = g4[(size_t)safe * 8 + c8];                      \
                }                                                           \
                _Pragma("unroll")                                           \
                for (int k = 0; k < 8; ++k) {                               \
                    const _Float16* hp = (const _Float16*)&vv[k];           \
                    accA.x += sel[k] * (float)hp[0];                        \
                    accA.y += sel[k] * (float)hp[1];                        \
                    accA.z += sel[k] * (float)hp[2];                        \
                    accA.w += sel[k] * (float)hp[3];                        \
                    accB.x += sel[k] * (float)hp[4];                        \
                    accB.y += sel[k] * (float)hp[5];                        \
                    accB.z += sel[k] * (float)hp[6];                        \
                    accB.w += sel[k] * (float)hp[7];                        \
                }                                                           \
            }                                                               \
            float4 oA = {accA.x * idg, accA.y * idg, accA.z * idg, accA.w * idg}; \
            float4 oB = {accB.x * idg, accB.y * idg, accB.z * idg, accB.w * idg}; \
            *(float4*)(sA + r * 68 + c8 * 8 + 0) = oA;                      \
            *(float4*)(sA + r * 68 + c8 * 8 + 4) = oB;                      \
        }                                                                   \
    }                                                                       \
    __syncthreads();                                                        \
    /* ---- phase B: register-blocked GEMM, W from global (L1-hot) ---- */  \
    const int r0 = t & 15;                                                  \
    const int jq = t >> 4;            /* j0/4 */                            \
    const int j0 = jq * 4;                                                  \
    const float4* __restrict__ Wl4 = (const float4*)Wl;                     \
    const float4* __restrict__ Wr4 = (const float4*)Wr;                     \
    const float4 bias = *(const float4*)(bl + j0);                          \
    float4 acc0 = bias, acc1 = bias, acc2 = bias, acc3 = bias;              \
    _Pragma("unroll 2")                                                     \
    for (int k4 = 0; k4 < 16; ++k4) {                                       \
        float4 b0 = Wl4[(4 * k4 + 0) * 16 + jq];                            \
        float4 b1 = Wl4[(4 * k4 + 1) * 16 + jq];                            \
        float4 b2 = Wl4[(4 * k4 + 2) * 16 + jq];                            \
        float4 b3 = Wl4[(4 * k4 + 3) * 16 + jq];                            \
        float4 a0 = *(const float4*)(sA + (r0 +  0) * 68 + 4 * k4);         \
        float4 a1 = *(const float4*)(sA + (r0 + 16) * 68 + 4 * k4);         \
        float4 a2 = *(const float4*)(sA + (r0 + 32) * 68 + 4 * k4);         \
        float4 a3 = *(const float4*)(sA + (r0 + 48) * 68 + 4 * k4);         \
        FMA4(acc0, a0, b0, b1, b2, b3)                                      \
        FMA4(acc1, a1, b0, b1, b2, b3)                                      \
        FMA4(acc2, a2, b0, b1, b2, b3)                                      \
        FMA4(acc3, a3, b0, b1, b2, b3)                                      \
        b0 = Wr4[(4 * k4 + 0) * 16 + jq];                                   \
        b1 = Wr4[(4 * k4 + 1) * 16 + jq];                                   \
        b2 = Wr4[(4 * k4 + 2) * 16 + jq];                                   \
        b3 = Wr4[(4 * k4 + 3) * 16 + jq];                                   \
        a0 = *(const float4*)(sS + (r0 +  0) * 68 + 4 * k4);                \
        a1 = *(const float4*)(sS + (r0 + 16) * 68 + 4 * k4);                \
        a2 = *(const float4*)(sS + (r0 + 32) * 68 + 4 * k4);                \
        a3 = *(const float4*)(sS + (r0 + 48) * 68 + 4 * k4);                \
        FMA4(acc0, a0, b0, b1, b2, b3)                                      \
        FMA4(acc1, a1, b0, b1, b2, b3)                                      \
        FMA4(acc2, a2, b0, b1, b2, b3)                                      \
        FMA4(acc3, a3, b0, b1, b2, b3)                                      \
    }                                                                       \
    acc0.x = (acc0.x > 0.f) ? acc0.x : SLOPE * acc0.x;                      \
    acc0.y = (acc0.y > 0.f) ? acc0.y : SLOPE * acc0.y;                      \
    acc0.z = (acc0.z > 0.f) ? acc0.z : SLOPE * acc0.z;                      \
    acc0.w = (acc0.w > 0.f) ? acc0.w : SLOPE * acc0.w;                      \
    acc1.x = (acc1.x > 0.f) ? acc1.x : SLOPE * acc1.x;                      \
    acc1.y = (acc1.y > 0.f) ? acc1.y : SLOPE * acc1.y;                      \
    acc1.z = (acc1.z > 0.f) ? acc1.z : SLOPE * acc1.z;                      \
    acc1.w = (acc1.w > 0.f) ? acc1.w : SLOPE * acc1.w;                      \
    acc2.x = (acc2.x > 0.f) ? acc2.x : SLOPE * acc2.x;                      \
    acc2.y = (acc2.y > 0.f) ? acc2.y : SLOPE * acc2.y;                      \
    acc2.z = (acc2.z > 0.f) ? acc2.z : SLOPE * acc2.z;                      \
    acc2.w = (acc2.w > 0.f) ? acc2.w : SLOPE * acc2.w;                      \
    acc3.x = (acc3.x > 0.f) ? acc3.x : SLOPE * acc3.x;                      \
    acc3.y = (acc3.y > 0.f) ? acc3.y : SLOPE * acc3.y;                      \
    acc3.z = (acc3.z > 0.f) ? acc3.z : SLOPE * acc3.z;                      \
    acc3.w = (acc3.w > 0.f) ? acc3.w : SLOPE * acc3.w;

__global__ __launch_bounds__(256, 4) void sage_fused(
    const _Float16* __restrict__ h16, const float* __restrict__ h_in,
    float* __restrict__ h_out, _Float16* __restrict__ h16_out,
    const int* __restrict__ rowptr, const int* __restrict__ rowend,
    const int* __restrict__ colidx, const float* __restrict__ invdeg,
    const float* __restrict__ Wl, const float* __restrict__ bl,
    const float* __restrict__ Wr, int n) {
    FUSED_BODY()
    #define STORE_ROW(S, ACC)                                               \
        { int r = r0 + 16 * S;                                              \
          if (r < rows) {                                                   \
              *(float4*)(h_out + (size_t)(base + r) * HD + j0) = ACC;       \
              _Float16 o[4] = {(_Float16)ACC.x, (_Float16)ACC.y,            \
                               (_Float16)ACC.z, (_Float16)ACC.w};           \
              *(float2*)(h16_out + (size_t)(base + r) * HD + j0)            \
                  = *(float2*)o;                                            \
          } }
    STORE_ROW(0, acc0)
    STORE_ROW(1, acc1)
    STORE_ROW(2, acc2)
    STORE_ROW(3, acc3)
    #undef STORE_ROW
}

// Layer-3 variant: h3 never hits memory — dot with Wout, cross-wave LDS
// reduction, write out[node] directly.
__global__ __launch_bounds__(256, 4) void sage_fused_out(
    const _Float16* __restrict__ h16, const float* __restrict__ h_in,
    const int* __restrict__ rowptr, const int* __restrict__ rowend,
    const int* __restrict__ colidx, const float* __restrict__ invdeg,
    const float* __restrict__ Wl, const float* __restrict__ bl,
    const float* __restrict__ Wr,
    const float* __restrict__ Wout, const float* __restrict__ bout,
    float* __restrict__ out, int n) {
    FUSED_BODY(__shared__ float s_part[16][64];)
    const float4 w4 = *(const float4*)(Wout + j0);
    s_part[jq][r0 +  0] = acc0.x * w4.x + acc0.y * w4.y + acc0.z * w4.z + acc0.w * w4.w;
    s_part[jq][r0 + 16] = acc1.x * w4.x + acc1.y * w4.y + acc1.z * w4.z + acc1.w * w4.w;
    s_part[jq][r0 + 32] = acc2.x * w4.x + acc2.y * w4.y + acc2.z * w4.z + acc2.w * w4.w;
    s_part[jq][r0 + 48] = acc3.x * w4.x + acc3.y * w4.y + acc3.z * w4.z + acc3.w * w4.w;
    __syncthreads();
    if (t < 64) {
        float sum = 0.f;
        #pragma unroll
        for (int g2 = 0; g2 < 16; ++g2) sum += s_part[g2][t];
        if (t < rows) out[base + t] = sum + bout[0];
    }
}

// ---------------------------------------------------------------------------

extern "C" void kernel_launch(void* const* d_in, const int* in_sizes, int n_in,
                              void* d_out, int out_size, void* d_ws, size_t ws_size,
                              hipStream_t stream) {
    const float* x   = (const float*)d_in[0];
    const int* ei    = (const int*)d_in[1];
    const float* Wl1 = (const float*)d_in[2];
    const float* bl1 = (const float*)d_in[3];
    const float* Wr1 = (const float*)d_in[4];
    const float* Wl2 = (const float*)d_in[5];
    const float* bl2 = (const float*)d_in[6];
    const float* Wr2 = (const float*)d_in[7];
    const float* Wl3 = (const float*)d_in[8];
    const float* bl3 = (const float*)d_in[9];
    const float* Wr3 = (const float*)d_in[10];
    const float* Wout = (const float*)d_in[11];
    const float* bout = (const float*)d_in[12];
    float* out = (float*)d_out;

    const int N = in_sizes[0] / HD;       // 50000
    const int E = in_sizes[1] / 2;        // 800000
    const int NB = (N + BNODES - 1) >> BSH;   // 782 buckets

    // Workspace layout — float4-accessed buffers first (16B alignment).
    float* hA     = (float*)d_ws;                    // [N*64] f32
    float* hB     = hA + (size_t)N * HD;             // [N*64] f32
    _Float16* h16a = (_Float16*)(hB + (size_t)N * HD);   // [N*64] f16
    _Float16* h16b = h16a + (size_t)N * HD;          // [N*64] f16
    int* ebuf     = (int*)(h16b + (size_t)N * HD);   // [NB*SLOT] packed edges
    int* colidx   = ebuf + (size_t)NB * SLOT;        // [NB*SLOT] padded CSR
    int* rowptr   = colidx + (size_t)NB * SLOT;      // [N]
    int* rowend   = rowptr + N;                      // [N]
    float* invdeg = (float*)(rowend + N);            // [N]
    int* bcur     = (int*)(invdeg + N);              // [784]

    hipMemsetAsync(bcur, 0, 784 * sizeof(int), stream);

    part_kernel<<<(E + CHUNK - 1) / CHUNK, 256, 0, stream>>>(ei, bcur, ebuf, E, NB);
    bsort_kernel<<<NB, 256, 0, stream>>>(ebuf, bcur, colidx, rowptr, rowend,
                                         invdeg, N);

    const int n64 = N * HD;
    tohalf_kernel<<<(n64 / 8 + 255) / 256, 256, 0, stream>>>(x, h16a, n64);

    const int ggrid = (N + 63) / 64;      // 782 tiles

    sage_fused<<<ggrid, 256, 0, stream>>>(h16a, x, hA, h16b,
                                          rowptr, rowend, colidx, invdeg,
                                          Wl1, bl1, Wr1, N);
    sage_fused<<<ggrid, 256, 0, stream>>>(h16b, hA, hB, h16a,
                                          rowptr, rowend, colidx, invdeg,
                                          Wl2, bl2, Wr2, N);
    sage_fused_out<<<ggrid, 256, 0, stream>>>(h16a, hB,
                                              rowptr, rowend, colidx, invdeg,
                                              Wl3, bl3, Wr3, Wout, bout, out, N);
}

// Round 14
// 205.021 us; speedup vs baseline: 5.9559x; 1.0592x over previous
//
#include <hip/hip_runtime.h>

#define HD 64
#define SLOPE 0.01f
#define BSH 6                    // 64 nodes per bucket
#define BNODES 64
#define CHUNK 4096               // edges per partition block
#define SLOT 1536                // padded edge capacity per bucket (exp max ~1150)

// ---------------------------------------------------------------------------
// Build v4 (R13-proven): padded-slot partition (no pre-count) -> per-bucket
// counting sort emitting padded CSR. bsort also folds the x->fp16 convert in
// its tail (independent work; the kernel boundary orders it before layer 1).
// ---------------------------------------------------------------------------

__global__ __launch_bounds__(256) void part_kernel(const int* __restrict__ ei,
                                                   int* __restrict__ bcur,
                                                   int* __restrict__ ebuf,
                                                   int E, int nb) {
    __shared__ int pk_s[CHUNK];
    __shared__ int mt_s[CHUNK];
    __shared__ int hist[784];
    __shared__ int sbase[784];
    const int t = threadIdx.x;
    const int c0 = blockIdx.x * CHUNK;
    const int cnt = min(CHUNK, E - c0);
    for (int i = t; i < nb; i += 256) hist[i] = 0;
    __syncthreads();
    for (int i = t; i < cnt; i += 256) {
        int src = ei[c0 + i];
        int dst = ei[E + c0 + i];
        int b = dst >> BSH;
        pk_s[i] = (src << BSH) | (dst & (BNODES - 1));
        int r = atomicAdd(&hist[b], 1);
        mt_s[i] = (b << 12) | r;           // rank < CHUNK = 2^12
    }
    __syncthreads();
    for (int b = t; b < nb; b += 256) {
        int h = hist[b];
        if (h) sbase[b] = b * SLOT + atomicAdd(&bcur[b], h);   // padded slot
    }
    __syncthreads();
    for (int i = t; i < cnt; i += 256) {
        int m = mt_s[i];
        int b = m >> 12;
        ebuf[sbase[b] + (m & (CHUNK - 1))] = pk_s[i];
    }
}

__global__ __launch_bounds__(256) void bsort_kernel(const int* __restrict__ ebuf,
                                                    const int* __restrict__ bcnt,
                                                    int* __restrict__ colidx,
                                                    int* __restrict__ rowptr,
                                                    int* __restrict__ rowend,
                                                    float* __restrict__ invdeg,
                                                    const float* __restrict__ x,
                                                    _Float16* __restrict__ h16a,
                                                    int n, int n64) {
    __shared__ int cnt[BNODES];
    const int b = blockIdx.x;
    const int t = threadIdx.x;
    const int ebeg = b * SLOT;
    const int eend = ebeg + bcnt[b];
    if (t < BNODES) cnt[t] = 0;
    __syncthreads();
    for (int k = ebeg + t; k < eend; k += 256)
        atomicAdd(&cnt[ebuf[k] & (BNODES - 1)], 1);
    __syncthreads();
    if (t < BNODES) {                      // wave 0: scan the 64 counters
        int v = cnt[t];
        int x2 = v;
        #pragma unroll
        for (int d = 1; d < 64; d <<= 1) { int y = __shfl_up(x2, d, 64); if (t >= d) x2 += y; }
        int excl = x2 - v;
        int node = b * BNODES + t;
        if (node < n) {
            rowptr[node] = ebeg + excl;
            rowend[node] = ebeg + excl + v;
            invdeg[node] = 1.0f / (float)((v > 1) ? v : 1);
        }
        cnt[t] = excl;                     // becomes the running cursor
    }
    __syncthreads();
    for (int k = ebeg + t; k < eend; k += 256) {
        int p = ebuf[k];
        int r = atomicAdd(&cnt[p & (BNODES - 1)], 1);
        colidx[ebeg + r] = p >> BSH;
    }
    // --- folded tohalf: x (f32) -> h16a, grid-stride, 8 elems/iter ---
    const int total8 = n64 >> 3;
    for (int i = b * 256 + t; i < total8; i += gridDim.x * 256) {
        int e = i * 8;
        float4 a = *(const float4*)(x + e);
        float4 c = *(const float4*)(x + e + 4);
        _Float16 o[8] = {(_Float16)a.x, (_Float16)a.y, (_Float16)a.z, (_Float16)a.w,
                         (_Float16)c.x, (_Float16)c.y, (_Float16)c.z, (_Float16)c.w};
        *(float4*)(h16a + e) = *(float4*)o;
    }
}

// ---------------------------------------------------------------------------
// Fused SAGE layer v3: ALL feature traffic fp16 (mean gather AND self path;
// fp32 h buffers deleted — saves 19 MB streaming/layer). Phase A = v6 gather
// (8 nodes/wave-pass, 8-lane groups, unconditional clamp-to-row-0 loads +
// select multiplier; all __shfl by ALL lanes — R3 lesson). Phase B =
// register-blocked GEMM, f32 accumulate, W straight from global (L1-hot,
// 256B-contig per instruction). LDS 34.8KB -> 4 blocks/CU (R13-proven).
// ---------------------------------------------------------------------------

#define FMA4(acc, am, b0, b1, b2, b3)                                  \
    acc.x += am.x * b0.x + am.y * b1.x + am.z * b2.x + am.w * b3.x;    \
    acc.y += am.x * b0.y + am.y * b1.y + am.z * b2.y + am.w * b3.y;    \
    acc.z += am.x * b0.z + am.y * b1.z + am.z * b2.z + am.w * b3.z;    \
    acc.w += am.x * b0.w + am.y * b1.w + am.z * b2.w + am.w * b3.w;

#define FUSED_BODY(EXTRA_SHARED)                                            \
    __shared__ float sA[64 * 68];     /* mean tile, f32, stride 68 */       \
    __shared__ float sS[64 * 68];     /* self tile, f32 */                  \
    EXTRA_SHARED                                                            \
    const int t = threadIdx.x;                                              \
    const int lane = t & 63;                                                \
    const int w = t >> 6;                                                   \
    const int base = blockIdx.x * 64;                                       \
    const int rows = min(64, n - base);                                     \
    const float4* __restrict__ g4 = (const float4*)h16_in;                  \
    /* stage self tile from fp16 (8KB streaming read, convert to f32) */    \
    _Pragma("unroll")                                                       \
    for (int idx = 0; idx < 2; ++idx) {                                     \
        int i = t + idx * 256;            /* 0..511 */                      \
        int r = i >> 3, cc = i & 7;                                         \
        float4 raw = {0.f, 0.f, 0.f, 0.f};                                  \
        if (r < rows) raw = g4[(size_t)(base + r) * 8 + cc];                \
        const _Float16* hp = (const _Float16*)&raw;                         \
        float4 lo = {(float)hp[0], (float)hp[1], (float)hp[2], (float)hp[3]}; \
        float4 hi = {(float)hp[4], (float)hp[5], (float)hp[6], (float)hp[7]}; \
        *(float4*)(sS + r * 68 + cc * 8 + 0) = lo;                          \
        *(float4*)(sS + r * 68 + cc * 8 + 4) = hi;                          \
    }                                                                       \
    /* ---- phase A: aggregate into sA ---- */                              \
    {                                                                       \
        const int g = lane >> 3;      /* node slot 0..7 */                  \
        const int c8 = lane & 7;      /* 16B chunk of 128B fp16 row */      \
        _Pragma("unroll")                                                   \
        for (int pass = 0; pass < 2; ++pass) {                              \
            const int r = w * 16 + pass * 8 + g;   /* local row 0..63 */    \
            const int node = base + r;                                      \
            const bool valid = node < n;                                    \
            int beg = 0, end = 0; float idg = 0.f;                          \
            if (valid) {                                                    \
                beg = rowptr[node];                                         \
                end = rowend[node];                                         \
                idg = invdeg[node];                                         \
            }                                                               \
            const int deg = end - beg;                                      \
            int md = deg;                       /* wave-uniform max */      \
            md = max(md, __shfl_xor(md, 8, 64));                            \
            md = max(md, __shfl_xor(md, 16, 64));                           \
            md = max(md, __shfl_xor(md, 32, 64));                           \
            float4 accA = {0.f, 0.f, 0.f, 0.f};                             \
            float4 accB = {0.f, 0.f, 0.f, 0.f};                             \
            for (int t0 = 0; t0 < md; t0 += 8) {                            \
                const int off = beg + t0 + c8;                              \
                int ci = (off < end) ? colidx[off] : 0;                     \
                int idx[8];                                                 \
                _Pragma("unroll")                                           \
                for (int k = 0; k < 8; ++k)                                 \
                    idx[k] = __shfl(ci, g * 8 + k, 64);                     \
                float4 vv[8];                                               \
                float sel[8];                                               \
                _Pragma("unroll")                                           \
                for (int k = 0; k < 8; ++k) {                               \
                    const bool p = (t0 + k) < deg;                          \
                    const int safe = p ? idx[k] : 0;                        \
                    sel[k] = p ? 1.0f : 0.0f;                               \
                    vv[k] = g4[(size_t)safe * 8 + c8];                      \
                }                                                           \
                _Pragma("unroll")                                           \
                for (int k = 0; k < 8; ++k) {                               \
                    const _Float16* hp = (const _Float16*)&vv[k];           \
                    accA.x += sel[k] * (float)hp[0];                        \
                    accA.y += sel[k] * (float)hp[1];                        \
                    accA.z += sel[k] * (float)hp[2];                        \
                    accA.w += sel[k] * (float)hp[3];                        \
                    accB.x += sel[k] * (float)hp[4];                        \
                    accB.y += sel[k] * (float)hp[5];                        \
                    accB.z += sel[k] * (float)hp[6];                        \
                    accB.w += sel[k] * (float)hp[7];                        \
                }                                                           \
            }                                                               \
            float4 oA = {accA.x * idg, accA.y * idg, accA.z * idg, accA.w * idg}; \
            float4 oB = {accB.x * idg, accB.y * idg, accB.z * idg, accB.w * idg}; \
            *(float4*)(sA + r * 68 + c8 * 8 + 0) = oA;                      \
            *(float4*)(sA + r * 68 + c8 * 8 + 4) = oB;                      \
        }                                                                   \
    }                                                                       \
    __syncthreads();                                                        \
    /* ---- phase B: register-blocked GEMM, W from global (L1-hot) ---- */  \
    const int r0 = t & 15;                                                  \
    const int jq = t >> 4;            /* j0/4 */                            \
    const int j0 = jq * 4;                                                  \
    const float4* __restrict__ Wl4 = (const float4*)Wl;                     \
    const float4* __restrict__ Wr4 = (const float4*)Wr;                     \
    const float4 bias = *(const float4*)(bl + j0);                          \
    float4 acc0 = bias, acc1 = bias, acc2 = bias, acc3 = bias;              \
    _Pragma("unroll 2")                                                     \
    for (int k4 = 0; k4 < 16; ++k4) {                                       \
        float4 b0 = Wl4[(4 * k4 + 0) * 16 + jq];                            \
        float4 b1 = Wl4[(4 * k4 + 1) * 16 + jq];                            \
        float4 b2 = Wl4[(4 * k4 + 2) * 16 + jq];                            \
        float4 b3 = Wl4[(4 * k4 + 3) * 16 + jq];                            \
        float4 a0 = *(const float4*)(sA + (r0 +  0) * 68 + 4 * k4);         \
        float4 a1 = *(const float4*)(sA + (r0 + 16) * 68 + 4 * k4);         \
        float4 a2 = *(const float4*)(sA + (r0 + 32) * 68 + 4 * k4);         \
        float4 a3 = *(const float4*)(sA + (r0 + 48) * 68 + 4 * k4);         \
        FMA4(acc0, a0, b0, b1, b2, b3)                                      \
        FMA4(acc1, a1, b0, b1, b2, b3)                                      \
        FMA4(acc2, a2, b0, b1, b2, b3)                                      \
        FMA4(acc3, a3, b0, b1, b2, b3)                                      \
        b0 = Wr4[(4 * k4 + 0) * 16 + jq];                                   \
        b1 = Wr4[(4 * k4 + 1) * 16 + jq];                                   \
        b2 = Wr4[(4 * k4 + 2) * 16 + jq];                                   \
        b3 = Wr4[(4 * k4 + 3) * 16 + jq];                                   \
        a0 = *(const float4*)(sS + (r0 +  0) * 68 + 4 * k4);                \
        a1 = *(const float4*)(sS + (r0 + 16) * 68 + 4 * k4);                \
        a2 = *(const float4*)(sS + (r0 + 32) * 68 + 4 * k4);                \
        a3 = *(const float4*)(sS + (r0 + 48) * 68 + 4 * k4);                \
        FMA4(acc0, a0, b0, b1, b2, b3)                                      \
        FMA4(acc1, a1, b0, b1, b2, b3)                                      \
        FMA4(acc2, a2, b0, b1, b2, b3)                                      \
        FMA4(acc3, a3, b0, b1, b2, b3)                                      \
    }                                                                       \
    acc0.x = (acc0.x > 0.f) ? acc0.x : SLOPE * acc0.x;                      \
    acc0.y = (acc0.y > 0.f) ? acc0.y : SLOPE * acc0.y;                      \
    acc0.z = (acc0.z > 0.f) ? acc0.z : SLOPE * acc0.z;                      \
    acc0.w = (acc0.w > 0.f) ? acc0.w : SLOPE * acc0.w;                      \
    acc1.x = (acc1.x > 0.f) ? acc1.x : SLOPE * acc1.x;                      \
    acc1.y = (acc1.y > 0.f) ? acc1.y : SLOPE * acc1.y;                      \
    acc1.z = (acc1.z > 0.f) ? acc1.z : SLOPE * acc1.z;                      \
    acc1.w = (acc1.w > 0.f) ? acc1.w : SLOPE * acc1.w;                      \
    acc2.x = (acc2.x > 0.f) ? acc2.x : SLOPE * acc2.x;                      \
    acc2.y = (acc2.y > 0.f) ? acc2.y : SLOPE * acc2.y;                      \
    acc2.z = (acc2.z > 0.f) ? acc2.z : SLOPE * acc2.z;                      \
    acc2.w = (acc2.w > 0.f) ? acc2.w : SLOPE * acc2.w;                      \
    acc3.x = (acc3.x > 0.f) ? acc3.x : SLOPE * acc3.x;                      \
    acc3.y = (acc3.y > 0.f) ? acc3.y : SLOPE * acc3.y;                      \
    acc3.z = (acc3.z > 0.f) ? acc3.z : SLOPE * acc3.z;                      \
    acc3.w = (acc3.w > 0.f) ? acc3.w : SLOPE * acc3.w;

__global__ __launch_bounds__(256, 4) void sage_fused(
    const _Float16* __restrict__ h16_in, _Float16* __restrict__ h16_out,
    const int* __restrict__ rowptr, const int* __restrict__ rowend,
    const int* __restrict__ colidx, const float* __restrict__ invdeg,
    const float* __restrict__ Wl, const float* __restrict__ bl,
    const float* __restrict__ Wr, int n) {
    FUSED_BODY()
    #define STORE_ROW(S, ACC)                                               \
        { int r = r0 + 16 * S;                                              \
          if (r < rows) {                                                   \
              _Float16 o[4] = {(_Float16)ACC.x, (_Float16)ACC.y,            \
                               (_Float16)ACC.z, (_Float16)ACC.w};           \
              *(float2*)(h16_out + (size_t)(base + r) * HD + j0)            \
                  = *(float2*)o;                                            \
          } }
    STORE_ROW(0, acc0)
    STORE_ROW(1, acc1)
    STORE_ROW(2, acc2)
    STORE_ROW(3, acc3)
    #undef STORE_ROW
}

// Layer-3 variant: h3 never hits memory — dot with Wout, cross-wave LDS
// reduction, write out[node] (f32) directly.
__global__ __launch_bounds__(256, 4) void sage_fused_out(
    const _Float16* __restrict__ h16_in,
    const int* __restrict__ rowptr, const int* __restrict__ rowend,
    const int* __restrict__ colidx, const float* __restrict__ invdeg,
    const float* __restrict__ Wl, const float* __restrict__ bl,
    const float* __restrict__ Wr,
    const float* __restrict__ Wout, const float* __restrict__ bout,
    float* __restrict__ out, int n) {
    FUSED_BODY(__shared__ float s_part[16][64];)
    const float4 w4 = *(const float4*)(Wout + j0);
    s_part[jq][r0 +  0] = acc0.x * w4.x + acc0.y * w4.y + acc0.z * w4.z + acc0.w * w4.w;
    s_part[jq][r0 + 16] = acc1.x * w4.x + acc1.y * w4.y + acc1.z * w4.z + acc1.w * w4.w;
    s_part[jq][r0 + 32] = acc2.x * w4.x + acc2.y * w4.y + acc2.z * w4.z + acc2.w * w4.w;
    s_part[jq][r0 + 48] = acc3.x * w4.x + acc3.y * w4.y + acc3.z * w4.z + acc3.w * w4.w;
    __syncthreads();
    if (t < 64) {
        float sum = 0.f;
        #pragma unroll
        for (int g2 = 0; g2 < 16; ++g2) sum += s_part[g2][t];
        if (t < rows) out[base + t] = sum + bout[0];
    }
}

// ---------------------------------------------------------------------------

extern "C" void kernel_launch(void* const* d_in, const int* in_sizes, int n_in,
                              void* d_out, int out_size, void* d_ws, size_t ws_size,
                              hipStream_t stream) {
    const float* x   = (const float*)d_in[0];
    const int* ei    = (const int*)d_in[1];
    const float* Wl1 = (const float*)d_in[2];
    const float* bl1 = (const float*)d_in[3];
    const float* Wr1 = (const float*)d_in[4];
    const float* Wl2 = (const float*)d_in[5];
    const float* bl2 = (const float*)d_in[6];
    const float* Wr2 = (const float*)d_in[7];
    const float* Wl3 = (const float*)d_in[8];
    const float* bl3 = (const float*)d_in[9];
    const float* Wr3 = (const float*)d_in[10];
    const float* Wout = (const float*)d_in[11];
    const float* bout = (const float*)d_in[12];
    float* out = (float*)d_out;

    const int N = in_sizes[0] / HD;       // 50000
    const int E = in_sizes[1] / 2;        // 800000
    const int NB = (N + BNODES - 1) >> BSH;   // 782 buckets
    const int n64 = N * HD;

    // Workspace layout — float4-accessed buffers first (16B alignment).
    _Float16* h16a = (_Float16*)d_ws;                // [N*64] f16
    _Float16* h16b = h16a + (size_t)N * HD;          // [N*64] f16
    int* ebuf     = (int*)(h16b + (size_t)N * HD);   // [NB*SLOT] packed edges
    int* colidx   = ebuf + (size_t)NB * SLOT;        // [NB*SLOT] padded CSR
    int* rowptr   = colidx + (size_t)NB * SLOT;      // [N]
    int* rowend   = rowptr + N;                      // [N]
    float* invdeg = (float*)(rowend + N);            // [N]
    int* bcur     = (int*)(invdeg + N);              // [784]

    hipMemsetAsync(bcur, 0, 784 * sizeof(int), stream);

    part_kernel<<<(E + CHUNK - 1) / CHUNK, 256, 0, stream>>>(ei, bcur, ebuf, E, NB);
    bsort_kernel<<<NB, 256, 0, stream>>>(ebuf, bcur, colidx, rowptr, rowend,
                                         invdeg, x, h16a, N, n64);

    const int ggrid = (N + 63) / 64;      // 782 tiles

    sage_fused<<<ggrid, 256, 0, stream>>>(h16a, h16b,
                                          rowptr, rowend, colidx, invdeg,
                                          Wl1, bl1, Wr1, N);
    sage_fused<<<ggrid, 256, 0, stream>>>(h16b, h16a,
                                          rowptr, rowend, colidx, invdeg,
                                          Wl2, bl2, Wr2, N);
    sage_fused_out<<<ggrid, 256, 0, stream>>>(h16a,
                                              rowptr, rowend, colidx, invdeg,
                                              Wl3, bl3, Wr3, Wout, bout, out, N);
}